// Round 3
// baseline (445.886 us; speedup 1.0000x reference)
//
#include <hip/hip_runtime.h>
#include <hip/hip_bf16.h>

typedef __bf16 bf16x8 __attribute__((ext_vector_type(8)));
typedef float f32x4 __attribute__((ext_vector_type(4)));

#define M_TOK 16384   // 8 * 2048 tokens
#define CHUNK 64
#define NCHUNK 32     // 2048 / 64

__device__ __forceinline__ void gload16(const void* g, void* l) {
    __builtin_amdgcn_global_load_lds(
        (const __attribute__((address_space(1))) void*)g,
        (__attribute__((address_space(3))) void*)l, 16, 0, 0);
}

__device__ __forceinline__ float sigmoidf_(float v) { return 1.f / (1.f + __expf(-v)); }

#define BARRIER __builtin_amdgcn_s_barrier()
#define LGKM0 do { asm volatile("s_waitcnt lgkmcnt(0)" ::: "memory"); __builtin_amdgcn_sched_barrier(0); } while (0)
#define VMC(n) asm volatile("s_waitcnt vmcnt(" #n ")" ::: "memory")

// ---------------- fp32 -> bf16 bulk convert (vectorized) ----------------
__global__ __launch_bounds__(256) void f32_to_bf16_k(const float* __restrict__ in,
                                                     __hip_bfloat16* __restrict__ out, int n8) {
    int i = blockIdx.x * 256 + threadIdx.x;
    if (i >= n8) return;
    const f32x4* p4 = reinterpret_cast<const f32x4*>(in) + (size_t)i * 2;
    f32x4 a = p4[0], b = p4[1];
    union { __hip_bfloat16 h[8]; uint4 u; } o;
    o.h[0] = __float2bfloat16(a[0]); o.h[1] = __float2bfloat16(a[1]);
    o.h[2] = __float2bfloat16(a[2]); o.h[3] = __float2bfloat16(a[3]);
    o.h[4] = __float2bfloat16(b[0]); o.h[5] = __float2bfloat16(b[1]);
    o.h[6] = __float2bfloat16(b[2]); o.h[7] = __float2bfloat16(b[3]);
    *reinterpret_cast<uint4*>(out + (size_t)i * 8) = o.u;
}

// ---------------- all 6 weight converts in ONE launch (blockIdx.y selects tensor) ----------------
__global__ __launch_bounds__(256)
void wconv6(const float* s0, const float* s1, const float* s2, const float* s3,
            const float* s4, const float* s5,
            __hip_bfloat16* d0, __hip_bfloat16* d1, __hip_bfloat16* d2,
            __hip_bfloat16* d3, __hip_bfloat16* d4, __hip_bfloat16* d5,
            int n0, int n1, int n2, int n3, int n4, int n5) {
    const float* src; __hip_bfloat16* dst; int n8;
    switch (blockIdx.y) {
        case 0: src = s0; dst = d0; n8 = n0; break;
        case 1: src = s1; dst = d1; n8 = n1; break;
        case 2: src = s2; dst = d2; n8 = n2; break;
        case 3: src = s3; dst = d3; n8 = n3; break;
        case 4: src = s4; dst = d4; n8 = n4; break;
        default: src = s5; dst = d5; n8 = n5; break;
    }
    int i = blockIdx.x * 256 + threadIdx.x;
    if (i >= n8) return;
    const f32x4* p4 = reinterpret_cast<const f32x4*>(src) + (size_t)i * 2;
    f32x4 a = p4[0], b = p4[1];
    union { __hip_bfloat16 h[8]; uint4 u; } o;
    o.h[0] = __float2bfloat16(a[0]); o.h[1] = __float2bfloat16(a[1]);
    o.h[2] = __float2bfloat16(a[2]); o.h[3] = __float2bfloat16(a[3]);
    o.h[4] = __float2bfloat16(b[0]); o.h[5] = __float2bfloat16(b[1]);
    o.h[6] = __float2bfloat16(b[2]); o.h[7] = __float2bfloat16(b[3]);
    *reinterpret_cast<uint4*>(dst + (size_t)i * 8) = o.u;
}

// ---------------- stage one half-tile (128 rows x 64 cols bf16), pre-swizzled source ----------------
// LDS dest is LINEAR [128][64] bf16 (row = 128 B). Logical element (r, colbyte c) must be
// readable at LDS byte r*128 + (c ^ swz(r)), swz(r) = ((r>>2)&3)<<5. Since gload_lds writes
// linearly (base + lane*16), we load from global col (c ^ swz) into linear col c (XOR involution).
__device__ __forceinline__ void stage_half(const __hip_bfloat16* src, int ldk, size_t row0,
                                           int k0, char* lds_half, int tid) {
    const int lane = tid & 63, wid = tid >> 6;
    #pragma unroll
    for (int l = 0; l < 2; ++l) {
        int q = wid * 2 + l;                 // 0..15 (1 KB chunk)
        int r = q * 8 + (lane >> 3);         // row within half
        int sw = ((r >> 2) & 3) << 5;        // swizzle (bytes)
        int cb = ((lane & 7) * 16) ^ sw;     // pre-swizzled source col byte
        const char* g = (const char*)(src + (row0 + r) * (size_t)ldk + k0) + cb;
        gload16(g, lds_half + q * 1024 + lane * 16);
    }
}

// ================= 256x256 8-phase pipelined GEMM: out = epi(X[M,K] @ W[N,K]^T + bias) =========
// MODE 0: silu -> bf16 (N=512, K=1024)
// MODE 1: sigmoid -> bf16 (N=1024, K=1024)
// MODE 2: final: (X@W^T + b + HS@CW^T + b2) * gate -> f32 (N=1024, K=1024+128)
//
// 8 waves (2M x 4N), strided wave tiling: A-frag m: row m*32+wm*16+lr (m 0..7);
// B-frag n: row n*64+wn*16+lr (n 0..3). Quadrant phases consume half-tiles progressively:
//   p0 (m0-3 x n0-1): A-half0 + B-half0  |  p1 (m4-7 x n0-1): A-half1
//   p2 (m4-7 x n2-3): B-half1            |  p3 (m0-3 x n2-3): (held regs)
// Staging order of tile kt+1 during kt: A0@p0, B0@p1, A1@p2, B1@p3 (2 loads each).
// Derived waits (per-wave outstanding): end-p0 vmcnt(4) [A1 ready], end-p1 vmcnt(4) [B1],
// end-p2 none, end-p3 vmcnt(4) [next A0,B0]. Last tile: (2, 0, none).
#define READ_A(ARR, MOFF)                                                      \
    { _Pragma("unroll") for (int m_ = 0; m_ < 4; ++m_)                         \
      _Pragma("unroll") for (int kk_ = 0; kk_ < 2; ++kk_)                      \
          ARR[m_][kk_] = frag(Ab, ((MOFF) + m_) * 32 + wm16 + lr, kk_); }
#define READ_B(NOFF)                                                           \
    { _Pragma("unroll") for (int n_ = 0; n_ < 2; ++n_)                         \
      _Pragma("unroll") for (int kk_ = 0; kk_ < 2; ++kk_)                      \
          bC[n_][kk_] = frag(Bb_, ((NOFF) + n_) * 64 + wn16 + lr, kk_); }
#define MFMA_Q(A, MB, NB)                                                      \
    { _Pragma("unroll") for (int kk_ = 0; kk_ < 2; ++kk_)                      \
      _Pragma("unroll") for (int m_ = 0; m_ < 4; ++m_)                         \
      _Pragma("unroll") for (int n_ = 0; n_ < 2; ++n_)                         \
          acc[(MB) + m_][(NB) + n_] = __builtin_amdgcn_mfma_f32_16x16x32_bf16( \
              A[m_][kk_], bC[n_][kk_], acc[(MB) + m_][(NB) + n_], 0, 0, 0); }
#define TILE_BODY(KT, STG, W0, W1, W3)                                         \
    {                                                                          \
        char* Ab  = smem + (((KT) & 1) ? 65536 : 0);                           \
        char* Bb_ = Ab + 32768;                                                \
        READ_A(aH, 0); READ_B(0);                                              \
        if (STG) stage(KT + 1, 0);                                             \
        BARRIER; LGKM0;                                                        \
        __builtin_amdgcn_s_setprio(1); MFMA_Q(aH, 0, 0); __builtin_amdgcn_s_setprio(0); \
        W0; BARRIER;                                                           \
        READ_A(aC, 4);                                                         \
        if (STG) stage(KT + 1, 1);                                             \
        BARRIER; LGKM0;                                                        \
        __builtin_amdgcn_s_setprio(1); MFMA_Q(aC, 4, 0); __builtin_amdgcn_s_setprio(0); \
        W1; BARRIER;                                                           \
        READ_B(2);                                                             \
        if (STG) stage(KT + 1, 2);                                             \
        BARRIER; LGKM0;                                                        \
        __builtin_amdgcn_s_setprio(1); MFMA_Q(aC, 4, 2); __builtin_amdgcn_s_setprio(0); \
        BARRIER;                                                               \
        if (STG) stage(KT + 1, 3);                                             \
        BARRIER; LGKM0;                                                        \
        __builtin_amdgcn_s_setprio(1); MFMA_Q(aH, 0, 2); __builtin_amdgcn_s_setprio(0); \
        W3; BARRIER;                                                           \
    }

template<int MODE>
__global__ __launch_bounds__(512, 2)
void gemm256(const __hip_bfloat16* __restrict__ X, const __hip_bfloat16* __restrict__ W,
             const float* __restrict__ bias, const float* __restrict__ bias2,
             const __hip_bfloat16* __restrict__ HS, const __hip_bfloat16* __restrict__ CW,
             const __hip_bfloat16* __restrict__ gate, float* __restrict__ outF,
             __hip_bfloat16* __restrict__ outB) {
    __shared__ char smem[131072];                 // 2 buffers x (A[256][64] + B[256][64]) bf16
    constexpr int N  = (MODE == 0) ? 512 : 1024;
    constexpr int NT = (MODE == 2) ? 18 : 16;     // MODE2: 16 K-tiles X@W + 2 K-tiles HS@CW
    constexpr int nN = N / 256;

    const int nwg  = gridDim.x;
    const int orig = blockIdx.x;
    const int v    = (orig & 7) * (nwg >> 3) + (orig >> 3);   // XCD-bijective (nwg%8==0)
    const size_t m0 = (size_t)(v / nN) * 256;
    const int    n0 = (v % nN) * 256;
    const int tid = threadIdx.x, lane = tid & 63, wid = tid >> 6;
    const int wm = wid >> 2, wn = wid & 3;
    const int lr = lane & 15, lg = lane >> 4;
    const int wm16 = wm * 16, wn16 = wn * 16;

    auto frag = [&](const char* base, int R, int kk2) -> bf16x8 {
        int cb = (kk2 * 64 + lg * 16) ^ (((R >> 2) & 3) << 5);
        return *reinterpret_cast<const bf16x8*>(base + R * 128 + cb);
    };
    auto stage = [&](int kt, int half) {
        char* buf = smem + ((kt & 1) ? 65536 : 0);
        bool cp = (MODE == 2) && (kt >= 16);
        const __hip_bfloat16* a = cp ? HS : X;
        const __hip_bfloat16* b = cp ? CW : W;
        int ldk = cp ? 128 : 1024;
        int k0  = cp ? (kt - 16) * 64 : kt * 64;
        switch (half) {
            case 0: stage_half(a, ldk, m0,             k0, buf,                 tid); break;
            case 1: stage_half(b, ldk, (size_t)n0,     k0, buf + 32768,         tid); break;
            case 2: stage_half(a, ldk, m0 + 128,       k0, buf + 16384,         tid); break;
            default: stage_half(b, ldk, (size_t)n0 + 128, k0, buf + 32768 + 16384, tid); break;
        }
    };

    f32x4 acc[8][4] = {};
    bf16x8 aH[4][2], aC[4][2], bC[2][2];

    // prologue: stage tile 0 (A0,B0,A1,B1), wait oldest 4 (A0,B0), enter pipeline
    stage(0, 0); stage(0, 1); stage(0, 2); stage(0, 3);
    VMC(4);
    BARRIER;

    for (int kt = 0; kt < NT - 1; ++kt)
        TILE_BODY(kt, true, VMC(4), VMC(4), VMC(4))
    TILE_BODY(NT - 1, false, VMC(2), VMC(0), (void)0)

    // epilogue
    #pragma unroll
    for (int m = 0; m < 8; ++m)
        #pragma unroll
        for (int n = 0; n < 4; ++n)
            #pragma unroll
            for (int rr = 0; rr < 4; ++rr) {
                size_t row = m0 + m * 32 + wm16 + lg * 4 + rr;
                int col = n0 + n * 64 + wn16 + lr;
                float vv = acc[m][n][rr] + bias[col];
                if constexpr (MODE == 0) {
                    outB[row * N + col] = __float2bfloat16(vv * sigmoidf_(vv));
                } else if constexpr (MODE == 1) {
                    outB[row * N + col] = __float2bfloat16(sigmoidf_(vv));
                } else {
                    float y = vv + bias2[col];
                    float gv = __bfloat162float(gate[row * 1024 + col]);
                    outF[row * 1024 + col] = y * gv;
                }
            }
}

// ---------------- u = (x@B_w^T + B_b) * sigmoid(z1@s_w2^T + s_b2)   [16384,128] ----------------
__global__ __launch_bounds__(256)
void gemm_u(const __hip_bfloat16* __restrict__ Z1, const __hip_bfloat16* __restrict__ W2,
            const float* __restrict__ b2,
            const __hip_bfloat16* __restrict__ X, const __hip_bfloat16* __restrict__ Bw,
            const float* __restrict__ Bb, __hip_bfloat16* __restrict__ U) {
    __shared__ __align__(16) __hip_bfloat16 As[64 * 64];
    __shared__ __align__(16) __hip_bfloat16 Bs[128 * 64];
    const int orig = blockIdx.x;                 // nwg = 256
    const int v = (orig & 7) * 32 + (orig >> 3);
    const int m0 = v * 64;
    const int tid = threadIdx.x;
    const int wid = tid >> 6, lane = tid & 63;
    const int wm = wid >> 1, wn = wid & 1;
    const int lr = lane & 15, lg = lane >> 4;
    const int srow = tid >> 3, sc8 = tid & 7;

    f32x4 accS[2][4] = {};
    for (int k0 = 0; k0 < 512; k0 += 64) {
        __syncthreads();
        #pragma unroll
        for (int j = 0; j < 2; ++j) {
            int row = srow + j * 32, q = tid + 256 * j;
            gload16(&Z1[(size_t)(m0 + row) * 512 + k0 + sc8 * 8], &As[q * 8]);
        }
        #pragma unroll
        for (int j = 0; j < 4; ++j) {
            int row = srow + j * 32, q = tid + 256 * j;
            gload16(&W2[(size_t)row * 512 + k0 + sc8 * 8], &Bs[q * 8]);
        }
        __syncthreads();
        #pragma unroll
        for (int kk = 0; kk < 2; ++kk) {
            bf16x8 af[2], bfr[4];
            #pragma unroll
            for (int m = 0; m < 2; ++m)
                af[m] = *reinterpret_cast<const bf16x8*>(&As[(wm*32 + m*16 + lr) * 64 + kk*32 + lg*8]);
            #pragma unroll
            for (int n = 0; n < 4; ++n)
                bfr[n] = *reinterpret_cast<const bf16x8*>(&Bs[(wn*64 + n*16 + lr) * 64 + kk*32 + lg*8]);
            #pragma unroll
            for (int m = 0; m < 2; ++m)
                #pragma unroll
                for (int n = 0; n < 4; ++n)
                    accS[m][n] = __builtin_amdgcn_mfma_f32_16x16x32_bf16(af[m], bfr[n], accS[m][n], 0, 0, 0);
        }
    }
    #pragma unroll
    for (int m = 0; m < 2; ++m)
        #pragma unroll
        for (int n = 0; n < 4; ++n)
            #pragma unroll
            for (int r = 0; r < 4; ++r) {
                int col = wn*64 + n*16 + lr;
                accS[m][n][r] = sigmoidf_(accS[m][n][r] + b2[col]);
            }
    f32x4 accU[2][4] = {};
    for (int k0 = 0; k0 < 1024; k0 += 64) {
        __syncthreads();
        #pragma unroll
        for (int j = 0; j < 2; ++j) {
            int row = srow + j * 32, q = tid + 256 * j;
            gload16(&X[(size_t)(m0 + row) * 1024 + k0 + sc8 * 8], &As[q * 8]);
        }
        #pragma unroll
        for (int j = 0; j < 4; ++j) {
            int row = srow + j * 32, q = tid + 256 * j;
            gload16(&Bw[(size_t)row * 1024 + k0 + sc8 * 8], &Bs[q * 8]);
        }
        __syncthreads();
        #pragma unroll
        for (int kk = 0; kk < 2; ++kk) {
            bf16x8 af[2], bfr[4];
            #pragma unroll
            for (int m = 0; m < 2; ++m)
                af[m] = *reinterpret_cast<const bf16x8*>(&As[(wm*32 + m*16 + lr) * 64 + kk*32 + lg*8]);
            #pragma unroll
            for (int n = 0; n < 4; ++n)
                bfr[n] = *reinterpret_cast<const bf16x8*>(&Bs[(wn*64 + n*16 + lr) * 64 + kk*32 + lg*8]);
            #pragma unroll
            for (int m = 0; m < 2; ++m)
                #pragma unroll
                for (int n = 0; n < 4; ++n)
                    accU[m][n] = __builtin_amdgcn_mfma_f32_16x16x32_bf16(af[m], bfr[n], accU[m][n], 0, 0, 0);
        }
    }
    #pragma unroll
    for (int m = 0; m < 2; ++m)
        #pragma unroll
        for (int n = 0; n < 4; ++n)
            #pragma unroll
            for (int r = 0; r < 4; ++r) {
                int row = m0 + wm*32 + m*16 + lg*4 + r;
                int col = wn*64 + n*16 + lr;
                float uval = (accU[m][n][r] + Bb[col]) * accS[m][n][r];
                U[(size_t)row * 128 + col] = __float2bfloat16(uval);
            }
}

// ---------------- A^64 by repeated squaring, single block (replaces 6 dependent launches) ---------
__global__ __launch_bounds__(1024) void apow64(const float* __restrict__ A,
                                               float* __restrict__ A64) {
    __shared__ float L[2 * 128 * 132];
    float* M0 = L; float* M1 = L + 128 * 132;
    const int tid = threadIdx.x;
    const int i = tid >> 3, jb = (tid & 7) * 16;
    for (int q = tid; q < 16384; q += 1024) M0[(q >> 7) * 132 + (q & 127)] = A[q];
    __syncthreads();
    float* src = M0; float* dst = M1;
    for (int it = 0; it < 6; ++it) {
        f32x4 acc[4] = {};
        const float* ri = src + i * 132;
        for (int k = 0; k < 128; ++k) {
            float a = ri[k];
            const f32x4* rk = reinterpret_cast<const f32x4*>(src + k * 132 + jb);
            #pragma unroll
            for (int c = 0; c < 4; ++c) acc[c] += a * rk[c];
        }
        #pragma unroll
        for (int c = 0; c < 4; ++c) *reinterpret_cast<f32x4*>(dst + i * 132 + jb + c * 4) = acc[c];
        __syncthreads();
        float* t = src; src = dst; dst = t;
    }
    for (int q = tid; q < 16384; q += 1024) A64[q] = src[(q >> 7) * 132 + (q & 127)];
}

// ---------------- chunked scan phase 1: local chunk-end states (zero init) ----------------
__global__ __launch_bounds__(128) void ssm_phase1(const float* __restrict__ A,
                                                  const __hip_bfloat16* __restrict__ u,
                                                  float* __restrict__ E) {
    __shared__ float Al[128 * 132];
    __shared__ __align__(16) float hbuf[2][128];
    const int tid = threadIdx.x;
    #pragma unroll 8
    for (int r = 0; r < 128; ++r) Al[r * 132 + tid] = A[r * 128 + tid];
    hbuf[0][tid] = 0.f;
    __syncthreads();
    const int b = blockIdx.x >> 5, c = blockIdx.x & 31;
    const __hip_bfloat16* up = u + ((size_t)b * 2048 + c * CHUNK) * 128;
    const f32x4* Arow = reinterpret_cast<const f32x4*>(&Al[tid * 132]);
    int cur = 0;
    for (int t = 0; t < CHUNK; ++t) {
        const f32x4* hv = reinterpret_cast<const f32x4*>(hbuf[cur]);
        f32x4 s4 = {0.f, 0.f, 0.f, 0.f};
        #pragma unroll
        for (int k = 0; k < 32; ++k) s4 += Arow[k] * hv[k];
        float val = s4[0] + s4[1] + s4[2] + s4[3] + __bfloat162float(up[t * 128 + tid]);
        hbuf[cur ^ 1][tid] = val;
        __syncthreads();
        cur ^= 1;
    }
    E[(size_t)blockIdx.x * 128 + tid] = hbuf[cur][tid];
}

// ---------------- phase 2: per-batch sequential combine across chunks with A^64 ----------------
__global__ __launch_bounds__(128) void ssm_phase2(const float* __restrict__ A64,
                                                  const float* __restrict__ E,
                                                  float* __restrict__ starts) {
    __shared__ float Al[128 * 132];
    __shared__ __align__(16) float st[2][128];
    const int tid = threadIdx.x;
    const int b = blockIdx.x;     // 8 blocks, one per batch
    #pragma unroll 8
    for (int r = 0; r < 128; ++r) Al[r * 132 + tid] = A64[r * 128 + tid];
    st[0][tid] = 0.f;
    __syncthreads();
    const f32x4* Arow = reinterpret_cast<const f32x4*>(&Al[tid * 132]);
    int cur = 0;
    for (int c = 0; c < NCHUNK; ++c) {
        starts[((size_t)b * NCHUNK + c) * 128 + tid] = st[cur][tid];
        const f32x4* hv = reinterpret_cast<const f32x4*>(st[cur]);
        f32x4 s4 = {0.f, 0.f, 0.f, 0.f};
        #pragma unroll
        for (int k = 0; k < 32; ++k) s4 += Arow[k] * hv[k];
        float val = s4[0] + s4[1] + s4[2] + s4[3] + E[((size_t)b * NCHUNK + c) * 128 + tid];
        st[cur ^ 1][tid] = val;
        __syncthreads();
        cur ^= 1;
    }
}

// ---------------- phase 3: re-run local scans from correct starts, emit hs (bf16) ----------------
__global__ __launch_bounds__(128) void ssm_phase3(const float* __restrict__ A,
                                                  const __hip_bfloat16* __restrict__ u,
                                                  const float* __restrict__ starts,
                                                  __hip_bfloat16* __restrict__ hs) {
    __shared__ float Al[128 * 132];
    __shared__ __align__(16) float hbuf[2][128];
    const int tid = threadIdx.x;
    #pragma unroll 8
    for (int r = 0; r < 128; ++r) Al[r * 132 + tid] = A[r * 128 + tid];
    hbuf[0][tid] = starts[(size_t)blockIdx.x * 128 + tid];
    __syncthreads();
    const int b = blockIdx.x >> 5, c = blockIdx.x & 31;
    const size_t tok0 = (size_t)b * 2048 + c * CHUNK;
    const __hip_bfloat16* up = u + tok0 * 128;
    const f32x4* Arow = reinterpret_cast<const f32x4*>(&Al[tid * 132]);
    int cur = 0;
    for (int t = 0; t < CHUNK; ++t) {
        const f32x4* hv = reinterpret_cast<const f32x4*>(hbuf[cur]);
        f32x4 s4 = {0.f, 0.f, 0.f, 0.f};
        #pragma unroll
        for (int k = 0; k < 32; ++k) s4 += Arow[k] * hv[k];
        float val = s4[0] + s4[1] + s4[2] + s4[3] + __bfloat162float(up[t * 128 + tid]);
        hs[(tok0 + t) * 128 + tid] = __float2bfloat16(val);
        hbuf[cur ^ 1][tid] = val;
        __syncthreads();
        cur ^= 1;
    }
}

// ---------------- host ----------------
extern "C" void kernel_launch(void* const* d_in, const int* in_sizes, int n_in,
                              void* d_out, int out_size, void* d_ws, size_t ws_size,
                              hipStream_t stream) {
    const float* x    = (const float*)d_in[0];
    const float* A    = (const float*)d_in[1];
    const float* B_w  = (const float*)d_in[2];
    const float* B_b  = (const float*)d_in[3];
    const float* C_w  = (const float*)d_in[4];
    const float* C_b  = (const float*)d_in[5];
    const float* D_w  = (const float*)d_in[6];
    const float* D_b  = (const float*)d_in[7];
    const float* s_w1 = (const float*)d_in[8];
    const float* s_b1 = (const float*)d_in[9];
    const float* s_w2 = (const float*)d_in[10];
    const float* s_b2 = (const float*)d_in[11];
    const float* g_w  = (const float*)d_in[12];
    const float* g_b  = (const float*)d_in[13];
    float* out = (float*)d_out;

    char* p = (char*)d_ws;
    auto alloc = [&](size_t n) { char* r = p; p += (n + 255) & ~(size_t)255; return r; };
    __hip_bfloat16* xb    = (__hip_bfloat16*)alloc((size_t)M_TOK * 1024 * 2);
    __hip_bfloat16* w1b   = (__hip_bfloat16*)alloc(512 * 1024 * 2);
    __hip_bfloat16* w2b   = (__hip_bfloat16*)alloc(128 * 512 * 2);
    __hip_bfloat16* Bwb   = (__hip_bfloat16*)alloc(128 * 1024 * 2);
    __hip_bfloat16* Cwb   = (__hip_bfloat16*)alloc(1024 * 128 * 2);
    __hip_bfloat16* Dwb   = (__hip_bfloat16*)alloc(1024 * 1024 * 2);
    __hip_bfloat16* gwb   = (__hip_bfloat16*)alloc(1024 * 1024 * 2);
    __hip_bfloat16* z1b   = (__hip_bfloat16*)alloc((size_t)M_TOK * 512 * 2);
    __hip_bfloat16* ub    = (__hip_bfloat16*)alloc((size_t)M_TOK * 128 * 2);
    __hip_bfloat16* hsb   = (__hip_bfloat16*)alloc((size_t)M_TOK * 128 * 2);
    __hip_bfloat16* gateb = (__hip_bfloat16*)alloc((size_t)M_TOK * 1024 * 2);
    float* pb       = (float*)alloc(128 * 128 * 4);
    float* Ebuf     = (float*)alloc(256 * 128 * 4);
    float* startbuf = (float*)alloc(256 * 128 * 4);

    // x -> bf16
    f32_to_bf16_k<<<dim3((M_TOK * 1024 / 8 + 255) / 256), dim3(256), 0, stream>>>(
        x, xb, M_TOK * 1024 / 8);
    // all weight converts, one launch
    wconv6<<<dim3(512, 6), dim3(256), 0, stream>>>(
        s_w1, s_w2, B_w, C_w, D_w, g_w,
        w1b, w2b, Bwb, Cwb, Dwb, gwb,
        512 * 1024 / 8, 128 * 512 / 8, 128 * 1024 / 8, 1024 * 128 / 8,
        1024 * 1024 / 8, 1024 * 1024 / 8);
    // A^64 (fp32 exact), single block
    apow64<<<1, 1024, 0, stream>>>(A, pb);

    // z1 = silu(x @ s_w1^T + s_b1)
    gemm256<0><<<dim3(128), dim3(512), 0, stream>>>(
        xb, w1b, s_b1, nullptr, nullptr, nullptr, nullptr, nullptr, z1b);
    // u = (x @ B_w^T + B_b) * sigmoid(z1 @ s_w2^T + s_b2)
    gemm_u<<<dim3(256), dim3(256), 0, stream>>>(z1b, w2b, s_b2, xb, Bwb, B_b, ub);

    // chunked scan
    ssm_phase1<<<256, 128, 0, stream>>>(A, ub, Ebuf);
    ssm_phase2<<<8, 128, 0, stream>>>(pb, Ebuf, startbuf);
    ssm_phase3<<<256, 128, 0, stream>>>(A, ub, startbuf, hsb);

    // gate = sigmoid(x @ g_w^T + g_b)  (bf16 buffer)
    gemm256<1><<<dim3(256), dim3(512), 0, stream>>>(
        xb, gwb, g_b, nullptr, nullptr, nullptr, nullptr, nullptr, gateb);
    // out = (x @ D_w^T + D_b + hs @ C_w^T + C_b) * gate
    gemm256<2><<<dim3(256), dim3(512), 0, stream>>>(
        xb, Dwb, D_b, C_b, hsb, Cwb, gateb, out, nullptr);
}

// Round 4
// 301.730 us; speedup vs baseline: 1.4778x; 1.4778x over previous
//
#include <hip/hip_runtime.h>
#include <hip/hip_bf16.h>

typedef __bf16 bf16x8 __attribute__((ext_vector_type(8)));
typedef float f32x4 __attribute__((ext_vector_type(4)));

#define M_TOK 16384   // 8 * 2048 tokens
#define CHUNK 64
#define NCHUNK 32     // 2048 / 64

__device__ __forceinline__ void gload16(const void* g, void* l) {
    __builtin_amdgcn_global_load_lds(
        (const __attribute__((address_space(1))) void*)g,
        (__attribute__((address_space(3))) void*)l, 16, 0, 0);
}

__device__ __forceinline__ float sigmoidf_(float v) { return 1.f / (1.f + __expf(-v)); }

#define BARRIER __builtin_amdgcn_s_barrier()
#define LGKM0 do { asm volatile("s_waitcnt lgkmcnt(0)" ::: "memory"); __builtin_amdgcn_sched_barrier(0); } while (0)
#define VMC(n) asm volatile("s_waitcnt vmcnt(" #n ")" ::: "memory")

// ---------------- fp32 -> bf16 bulk convert (vectorized) ----------------
__global__ __launch_bounds__(256) void f32_to_bf16_k(const float* __restrict__ in,
                                                     __hip_bfloat16* __restrict__ out, int n8) {
    int i = blockIdx.x * 256 + threadIdx.x;
    if (i >= n8) return;
    const f32x4* p4 = reinterpret_cast<const f32x4*>(in) + (size_t)i * 2;
    f32x4 a = p4[0], b = p4[1];
    union { __hip_bfloat16 h[8]; uint4 u; } o;
    o.h[0] = __float2bfloat16(a[0]); o.h[1] = __float2bfloat16(a[1]);
    o.h[2] = __float2bfloat16(a[2]); o.h[3] = __float2bfloat16(a[3]);
    o.h[4] = __float2bfloat16(b[0]); o.h[5] = __float2bfloat16(b[1]);
    o.h[6] = __float2bfloat16(b[2]); o.h[7] = __float2bfloat16(b[3]);
    *reinterpret_cast<uint4*>(out + (size_t)i * 8) = o.u;
}

// ---------------- all 6 weight converts in ONE launch (blockIdx.y selects tensor) ----------------
__global__ __launch_bounds__(256)
void wconv6(const float* s0, const float* s1, const float* s2, const float* s3,
            const float* s4, const float* s5,
            __hip_bfloat16* d0, __hip_bfloat16* d1, __hip_bfloat16* d2,
            __hip_bfloat16* d3, __hip_bfloat16* d4, __hip_bfloat16* d5,
            int n0, int n1, int n2, int n3, int n4, int n5) {
    const float* src; __hip_bfloat16* dst; int n8;
    switch (blockIdx.y) {
        case 0: src = s0; dst = d0; n8 = n0; break;
        case 1: src = s1; dst = d1; n8 = n1; break;
        case 2: src = s2; dst = d2; n8 = n2; break;
        case 3: src = s3; dst = d3; n8 = n3; break;
        case 4: src = s4; dst = d4; n8 = n4; break;
        default: src = s5; dst = d5; n8 = n5; break;
    }
    int i = blockIdx.x * 256 + threadIdx.x;
    if (i >= n8) return;
    const f32x4* p4 = reinterpret_cast<const f32x4*>(src) + (size_t)i * 2;
    f32x4 a = p4[0], b = p4[1];
    union { __hip_bfloat16 h[8]; uint4 u; } o;
    o.h[0] = __float2bfloat16(a[0]); o.h[1] = __float2bfloat16(a[1]);
    o.h[2] = __float2bfloat16(a[2]); o.h[3] = __float2bfloat16(a[3]);
    o.h[4] = __float2bfloat16(b[0]); o.h[5] = __float2bfloat16(b[1]);
    o.h[6] = __float2bfloat16(b[2]); o.h[7] = __float2bfloat16(b[3]);
    *reinterpret_cast<uint4*>(dst + (size_t)i * 8) = o.u;
}

// ---------------- stage one half-tile (128 rows x 64 cols bf16), pre-swizzled source ----------------
// LDS dest is LINEAR [128][64] bf16 (row = 128 B). Logical element (r, colbyte c) must be
// readable at LDS byte r*128 + (c ^ swz(r)), swz(r) = ((r>>2)&3)<<5. Since gload_lds writes
// linearly (base + lane*16), we load from global col (c ^ swz) into linear col c (XOR involution).
__device__ __forceinline__ void stage_half(const __hip_bfloat16* src, int ldk, size_t row0,
                                           int k0, char* lds_half, int tid) {
    const int lane = tid & 63, wid = tid >> 6;
    #pragma unroll
    for (int l = 0; l < 2; ++l) {
        int q = wid * 2 + l;                 // 0..15 (1 KB chunk)
        int r = q * 8 + (lane >> 3);         // row within half
        int sw = ((r >> 2) & 3) << 5;        // swizzle (bytes)
        int cb = ((lane & 7) * 16) ^ sw;     // pre-swizzled source col byte
        const char* g = (const char*)(src + (row0 + r) * (size_t)ldk + k0) + cb;
        gload16(g, lds_half + q * 1024 + lane * 16);
    }
}

// ================= 256x256 8-phase pipelined GEMM: out = epi(X[M,K] @ W[N,K]^T + bias) =========
// MODE 0: silu -> bf16 (N=512, K=1024)
// MODE 1: sigmoid -> bf16 (N=1024, K=1024)
// MODE 2: final: (X@W^T + b + HS@CW^T + b2) * gate -> f32 (N=1024, K=1024+128)
#define READ_A(ARR, MOFF)                                                      \
    { _Pragma("unroll") for (int m_ = 0; m_ < 4; ++m_)                         \
      _Pragma("unroll") for (int kk_ = 0; kk_ < 2; ++kk_)                      \
          ARR[m_][kk_] = frag(Ab, ((MOFF) + m_) * 32 + wm16 + lr, kk_); }
#define READ_B(NOFF)                                                           \
    { _Pragma("unroll") for (int n_ = 0; n_ < 2; ++n_)                         \
      _Pragma("unroll") for (int kk_ = 0; kk_ < 2; ++kk_)                      \
          bC[n_][kk_] = frag(Bb_, ((NOFF) + n_) * 64 + wn16 + lr, kk_); }
#define MFMA_Q(A, MB, NB)                                                      \
    { _Pragma("unroll") for (int kk_ = 0; kk_ < 2; ++kk_)                      \
      _Pragma("unroll") for (int m_ = 0; m_ < 4; ++m_)                         \
      _Pragma("unroll") for (int n_ = 0; n_ < 2; ++n_)                         \
          acc[(MB) + m_][(NB) + n_] = __builtin_amdgcn_mfma_f32_16x16x32_bf16( \
              A[m_][kk_], bC[n_][kk_], acc[(MB) + m_][(NB) + n_], 0, 0, 0); }
#define TILE_BODY(KT, STG, W0, W1, W3)                                         \
    {                                                                          \
        char* Ab  = smem + (((KT) & 1) ? 65536 : 0);                           \
        char* Bb_ = Ab + 32768;                                                \
        READ_A(aH, 0); READ_B(0);                                              \
        if (STG) stage(KT + 1, 0);                                             \
        BARRIER; LGKM0;                                                        \
        __builtin_amdgcn_s_setprio(1); MFMA_Q(aH, 0, 0); __builtin_amdgcn_s_setprio(0); \
        W0; BARRIER;                                                           \
        READ_A(aC, 4);                                                         \
        if (STG) stage(KT + 1, 1);                                             \
        BARRIER; LGKM0;                                                        \
        __builtin_amdgcn_s_setprio(1); MFMA_Q(aC, 4, 0); __builtin_amdgcn_s_setprio(0); \
        W1; BARRIER;                                                           \
        READ_B(2);                                                             \
        if (STG) stage(KT + 1, 2);                                             \
        BARRIER; LGKM0;                                                        \
        __builtin_amdgcn_s_setprio(1); MFMA_Q(aC, 4, 2); __builtin_amdgcn_s_setprio(0); \
        BARRIER;                                                               \
        if (STG) stage(KT + 1, 3);                                             \
        BARRIER; LGKM0;                                                        \
        __builtin_amdgcn_s_setprio(1); MFMA_Q(aH, 0, 2); __builtin_amdgcn_s_setprio(0); \
        W3; BARRIER;                                                           \
    }

template<int MODE>
__global__ __launch_bounds__(512, 2)
void gemm256(const __hip_bfloat16* __restrict__ X, const __hip_bfloat16* __restrict__ W,
             const float* __restrict__ bias, const float* __restrict__ bias2,
             const __hip_bfloat16* __restrict__ HS, const __hip_bfloat16* __restrict__ CW,
             const __hip_bfloat16* __restrict__ gate, float* __restrict__ outF,
             __hip_bfloat16* __restrict__ outB) {
    __shared__ char smem[131072];                 // 2 buffers x (A[256][64] + B[256][64]) bf16
    constexpr int N  = (MODE == 0) ? 512 : 1024;
    constexpr int NT = (MODE == 2) ? 18 : 16;     // MODE2: 16 K-tiles X@W + 2 K-tiles HS@CW
    constexpr int nN = N / 256;

    const int nwg  = gridDim.x;
    const int orig = blockIdx.x;
    const int v    = (orig & 7) * (nwg >> 3) + (orig >> 3);   // XCD-bijective (nwg%8==0)
    const size_t m0 = (size_t)(v / nN) * 256;
    const int    n0 = (v % nN) * 256;
    const int tid = threadIdx.x, lane = tid & 63, wid = tid >> 6;
    const int wm = wid >> 2, wn = wid & 3;
    const int lr = lane & 15, lg = lane >> 4;
    const int wm16 = wm * 16, wn16 = wn * 16;

    auto frag = [&](const char* base, int R, int kk2) -> bf16x8 {
        int cb = (kk2 * 64 + lg * 16) ^ (((R >> 2) & 3) << 5);
        return *reinterpret_cast<const bf16x8*>(base + R * 128 + cb);
    };
    auto stage = [&](int kt, int half) {
        char* buf = smem + ((kt & 1) ? 65536 : 0);
        bool cp = (MODE == 2) && (kt >= 16);
        const __hip_bfloat16* a = cp ? HS : X;
        const __hip_bfloat16* b = cp ? CW : W;
        int ldk = cp ? 128 : 1024;
        int k0  = cp ? (kt - 16) * 64 : kt * 64;
        switch (half) {
            case 0: stage_half(a, ldk, m0,             k0, buf,                 tid); break;
            case 1: stage_half(b, ldk, (size_t)n0,     k0, buf + 32768,         tid); break;
            case 2: stage_half(a, ldk, m0 + 128,       k0, buf + 16384,         tid); break;
            default: stage_half(b, ldk, (size_t)n0 + 128, k0, buf + 32768 + 16384, tid); break;
        }
    };

    f32x4 acc[8][4] = {};
    bf16x8 aH[4][2], aC[4][2], bC[2][2];

    // prologue: stage tile 0 (A0,B0,A1,B1), wait oldest 4 (A0,B0), enter pipeline
    stage(0, 0); stage(0, 1); stage(0, 2); stage(0, 3);
    VMC(4);
    BARRIER;

    for (int kt = 0; kt < NT - 1; ++kt)
        TILE_BODY(kt, true, VMC(4), VMC(4), VMC(4))
    TILE_BODY(NT - 1, false, VMC(2), VMC(0), (void)0)

    // epilogue
    #pragma unroll
    for (int m = 0; m < 8; ++m)
        #pragma unroll
        for (int n = 0; n < 4; ++n)
            #pragma unroll
            for (int rr = 0; rr < 4; ++rr) {
                size_t row = m0 + m * 32 + wm16 + lg * 4 + rr;
                int col = n0 + n * 64 + wn16 + lr;
                float vv = acc[m][n][rr] + bias[col];
                if constexpr (MODE == 0) {
                    outB[row * N + col] = __float2bfloat16(vv * sigmoidf_(vv));
                } else if constexpr (MODE == 1) {
                    outB[row * N + col] = __float2bfloat16(sigmoidf_(vv));
                } else {
                    float y = vv + bias2[col];
                    float gv = __bfloat162float(gate[row * 1024 + col]);
                    outF[row * 1024 + col] = y * gv;
                }
            }
}

// ---------------- u = (x@B_w^T + B_b) * sigmoid(z1@s_w2^T + s_b2)   [16384,128] ----------------
__global__ __launch_bounds__(256)
void gemm_u(const __hip_bfloat16* __restrict__ Z1, const __hip_bfloat16* __restrict__ W2,
            const float* __restrict__ b2,
            const __hip_bfloat16* __restrict__ X, const __hip_bfloat16* __restrict__ Bw,
            const float* __restrict__ Bb, __hip_bfloat16* __restrict__ U) {
    __shared__ __align__(16) __hip_bfloat16 As[64 * 64];
    __shared__ __align__(16) __hip_bfloat16 Bs[128 * 64];
    const int orig = blockIdx.x;                 // nwg = 256
    const int v = (orig & 7) * 32 + (orig >> 3);
    const int m0 = v * 64;
    const int tid = threadIdx.x;
    const int wid = tid >> 6, lane = tid & 63;
    const int wm = wid >> 1, wn = wid & 1;
    const int lr = lane & 15, lg = lane >> 4;
    const int srow = tid >> 3, sc8 = tid & 7;

    f32x4 accS[2][4] = {};
    for (int k0 = 0; k0 < 512; k0 += 64) {
        __syncthreads();
        #pragma unroll
        for (int j = 0; j < 2; ++j) {
            int row = srow + j * 32, q = tid + 256 * j;
            gload16(&Z1[(size_t)(m0 + row) * 512 + k0 + sc8 * 8], &As[q * 8]);
        }
        #pragma unroll
        for (int j = 0; j < 4; ++j) {
            int row = srow + j * 32, q = tid + 256 * j;
            gload16(&W2[(size_t)row * 512 + k0 + sc8 * 8], &Bs[q * 8]);
        }
        __syncthreads();
        #pragma unroll
        for (int kk = 0; kk < 2; ++kk) {
            bf16x8 af[2], bfr[4];
            #pragma unroll
            for (int m = 0; m < 2; ++m)
                af[m] = *reinterpret_cast<const bf16x8*>(&As[(wm*32 + m*16 + lr) * 64 + kk*32 + lg*8]);
            #pragma unroll
            for (int n = 0; n < 4; ++n)
                bfr[n] = *reinterpret_cast<const bf16x8*>(&Bs[(wn*64 + n*16 + lr) * 64 + kk*32 + lg*8]);
            #pragma unroll
            for (int m = 0; m < 2; ++m)
                #pragma unroll
                for (int n = 0; n < 4; ++n)
                    accS[m][n] = __builtin_amdgcn_mfma_f32_16x16x32_bf16(af[m], bfr[n], accS[m][n], 0, 0, 0);
        }
    }
    #pragma unroll
    for (int m = 0; m < 2; ++m)
        #pragma unroll
        for (int n = 0; n < 4; ++n)
            #pragma unroll
            for (int r = 0; r < 4; ++r) {
                int col = wn*64 + n*16 + lr;
                accS[m][n][r] = sigmoidf_(accS[m][n][r] + b2[col]);
            }
    f32x4 accU[2][4] = {};
    for (int k0 = 0; k0 < 1024; k0 += 64) {
        __syncthreads();
        #pragma unroll
        for (int j = 0; j < 2; ++j) {
            int row = srow + j * 32, q = tid + 256 * j;
            gload16(&X[(size_t)(m0 + row) * 1024 + k0 + sc8 * 8], &As[q * 8]);
        }
        #pragma unroll
        for (int j = 0; j < 4; ++j) {
            int row = srow + j * 32, q = tid + 256 * j;
            gload16(&Bw[(size_t)row * 1024 + k0 + sc8 * 8], &Bs[q * 8]);
        }
        __syncthreads();
        #pragma unroll
        for (int kk = 0; kk < 2; ++kk) {
            bf16x8 af[2], bfr[4];
            #pragma unroll
            for (int m = 0; m < 2; ++m)
                af[m] = *reinterpret_cast<const bf16x8*>(&As[(wm*32 + m*16 + lr) * 64 + kk*32 + lg*8]);
            #pragma unroll
            for (int n = 0; n < 4; ++n)
                bfr[n] = *reinterpret_cast<const bf16x8*>(&Bs[(wn*64 + n*16 + lr) * 64 + kk*32 + lg*8]);
            #pragma unroll
            for (int m = 0; m < 2; ++m)
                #pragma unroll
                for (int n = 0; n < 4; ++n)
                    accU[m][n] = __builtin_amdgcn_mfma_f32_16x16x32_bf16(af[m], bfr[n], accU[m][n], 0, 0, 0);
        }
    }
    #pragma unroll
    for (int m = 0; m < 2; ++m)
        #pragma unroll
        for (int n = 0; n < 4; ++n)
            #pragma unroll
            for (int r = 0; r < 4; ++r) {
                int row = m0 + wm*32 + m*16 + lg*4 + r;
                int col = wn*64 + n*16 + lr;
                float uval = (accU[m][n][r] + Bb[col]) * accS[m][n][r];
                U[(size_t)row * 128 + col] = __float2bfloat16(uval);
            }
}

// ---------------- 128x128x128 fp32 matmul (for A^2,A^4,...,A^64) ----------------
// 128 blocks x 128 threads, L2-resident data: ~4 us/launch. Do NOT fuse into one
// block (R2 regression: single-CU LDS-BW-bound apow64 = 180 us).
__global__ __launch_bounds__(128) void matmul128(const float* __restrict__ P,
                                                 const float* __restrict__ Q,
                                                 float* __restrict__ O) {
    int i = blockIdx.x, j = threadIdx.x;
    float acc = 0.f;
    #pragma unroll 8
    for (int k = 0; k < 128; ++k)
        acc = fmaf(P[i * 128 + k], Q[k * 128 + j], acc);
    O[i * 128 + j] = acc;
}

// ---------------- chunked scan phase 1: local chunk-end states (zero init) ----------------
__global__ __launch_bounds__(128) void ssm_phase1(const float* __restrict__ A,
                                                  const __hip_bfloat16* __restrict__ u,
                                                  float* __restrict__ E) {
    __shared__ float Al[128 * 132];
    __shared__ __align__(16) float hbuf[2][128];
    const int tid = threadIdx.x;
    #pragma unroll 8
    for (int r = 0; r < 128; ++r) Al[r * 132 + tid] = A[r * 128 + tid];
    hbuf[0][tid] = 0.f;
    __syncthreads();
    const int b = blockIdx.x >> 5, c = blockIdx.x & 31;
    const __hip_bfloat16* up = u + ((size_t)b * 2048 + c * CHUNK) * 128;
    const f32x4* Arow = reinterpret_cast<const f32x4*>(&Al[tid * 132]);
    int cur = 0;
    for (int t = 0; t < CHUNK; ++t) {
        const f32x4* hv = reinterpret_cast<const f32x4*>(hbuf[cur]);
        f32x4 s4 = {0.f, 0.f, 0.f, 0.f};
        #pragma unroll
        for (int k = 0; k < 32; ++k) s4 += Arow[k] * hv[k];
        float val = s4[0] + s4[1] + s4[2] + s4[3] + __bfloat162float(up[t * 128 + tid]);
        hbuf[cur ^ 1][tid] = val;
        __syncthreads();
        cur ^= 1;
    }
    E[(size_t)blockIdx.x * 128 + tid] = hbuf[cur][tid];
}

// ---------------- phase 2: per-batch sequential combine across chunks with A^64 ----------------
__global__ __launch_bounds__(128) void ssm_phase2(const float* __restrict__ A64,
                                                  const float* __restrict__ E,
                                                  float* __restrict__ starts) {
    __shared__ float Al[128 * 132];
    __shared__ __align__(16) float st[2][128];
    const int tid = threadIdx.x;
    const int b = blockIdx.x;     // 8 blocks, one per batch
    #pragma unroll 8
    for (int r = 0; r < 128; ++r) Al[r * 132 + tid] = A64[r * 128 + tid];
    st[0][tid] = 0.f;
    __syncthreads();
    const f32x4* Arow = reinterpret_cast<const f32x4*>(&Al[tid * 132]);
    int cur = 0;
    for (int c = 0; c < NCHUNK; ++c) {
        starts[((size_t)b * NCHUNK + c) * 128 + tid] = st[cur][tid];
        const f32x4* hv = reinterpret_cast<const f32x4*>(st[cur]);
        f32x4 s4 = {0.f, 0.f, 0.f, 0.f};
        #pragma unroll
        for (int k = 0; k < 32; ++k) s4 += Arow[k] * hv[k];
        float val = s4[0] + s4[1] + s4[2] + s4[3] + E[((size_t)b * NCHUNK + c) * 128 + tid];
        st[cur ^ 1][tid] = val;
        __syncthreads();
        cur ^= 1;
    }
}

// ---------------- phase 3: re-run local scans from correct starts, emit hs (bf16) ----------------
__global__ __launch_bounds__(128) void ssm_phase3(const float* __restrict__ A,
                                                  const __hip_bfloat16* __restrict__ u,
                                                  const float* __restrict__ starts,
                                                  __hip_bfloat16* __restrict__ hs) {
    __shared__ float Al[128 * 132];
    __shared__ __align__(16) float hbuf[2][128];
    const int tid = threadIdx.x;
    #pragma unroll 8
    for (int r = 0; r < 128; ++r) Al[r * 132 + tid] = A[r * 128 + tid];
    hbuf[0][tid] = starts[(size_t)blockIdx.x * 128 + tid];
    __syncthreads();
    const int b = blockIdx.x >> 5, c = blockIdx.x & 31;
    const size_t tok0 = (size_t)b * 2048 + c * CHUNK;
    const __hip_bfloat16* up = u + tok0 * 128;
    const f32x4* Arow = reinterpret_cast<const f32x4*>(&Al[tid * 132]);
    int cur = 0;
    for (int t = 0; t < CHUNK; ++t) {
        const f32x4* hv = reinterpret_cast<const f32x4*>(hbuf[cur]);
        f32x4 s4 = {0.f, 0.f, 0.f, 0.f};
        #pragma unroll
        for (int k = 0; k < 32; ++k) s4 += Arow[k] * hv[k];
        float val = s4[0] + s4[1] + s4[2] + s4[3] + __bfloat162float(up[t * 128 + tid]);
        hs[(tok0 + t) * 128 + tid] = __float2bfloat16(val);
        hbuf[cur ^ 1][tid] = val;
        __syncthreads();
        cur ^= 1;
    }
}

// ---------------- host ----------------
extern "C" void kernel_launch(void* const* d_in, const int* in_sizes, int n_in,
                              void* d_out, int out_size, void* d_ws, size_t ws_size,
                              hipStream_t stream) {
    const float* x    = (const float*)d_in[0];
    const float* A    = (const float*)d_in[1];
    const float* B_w  = (const float*)d_in[2];
    const float* B_b  = (const float*)d_in[3];
    const float* C_w  = (const float*)d_in[4];
    const float* C_b  = (const float*)d_in[5];
    const float* D_w  = (const float*)d_in[6];
    const float* D_b  = (const float*)d_in[7];
    const float* s_w1 = (const float*)d_in[8];
    const float* s_b1 = (const float*)d_in[9];
    const float* s_w2 = (const float*)d_in[10];
    const float* s_b2 = (const float*)d_in[11];
    const float* g_w  = (const float*)d_in[12];
    const float* g_b  = (const float*)d_in[13];
    float* out = (float*)d_out;

    char* p = (char*)d_ws;
    auto alloc = [&](size_t n) { char* r = p; p += (n + 255) & ~(size_t)255; return r; };
    __hip_bfloat16* xb    = (__hip_bfloat16*)alloc((size_t)M_TOK * 1024 * 2);
    __hip_bfloat16* w1b   = (__hip_bfloat16*)alloc(512 * 1024 * 2);
    __hip_bfloat16* w2b   = (__hip_bfloat16*)alloc(128 * 512 * 2);
    __hip_bfloat16* Bwb   = (__hip_bfloat16*)alloc(128 * 1024 * 2);
    __hip_bfloat16* Cwb   = (__hip_bfloat16*)alloc(1024 * 128 * 2);
    __hip_bfloat16* Dwb   = (__hip_bfloat16*)alloc(1024 * 1024 * 2);
    __hip_bfloat16* gwb   = (__hip_bfloat16*)alloc(1024 * 1024 * 2);
    __hip_bfloat16* z1b   = (__hip_bfloat16*)alloc((size_t)M_TOK * 512 * 2);
    __hip_bfloat16* ub    = (__hip_bfloat16*)alloc((size_t)M_TOK * 128 * 2);
    __hip_bfloat16* hsb   = (__hip_bfloat16*)alloc((size_t)M_TOK * 128 * 2);
    __hip_bfloat16* gateb = (__hip_bfloat16*)alloc((size_t)M_TOK * 1024 * 2);
    float* pa       = (float*)alloc(128 * 128 * 4);
    float* pb       = (float*)alloc(128 * 128 * 4);
    float* Ebuf     = (float*)alloc(256 * 128 * 4);
    float* startbuf = (float*)alloc(256 * 128 * 4);

    // A^64 by repeated squaring (fp32 exact) — 6 tiny launches, L2-resident
    matmul128<<<128, 128, 0, stream>>>(A,  A,  pa);   // A^2
    matmul128<<<128, 128, 0, stream>>>(pa, pa, pb);   // A^4
    matmul128<<<128, 128, 0, stream>>>(pb, pb, pa);   // A^8
    matmul128<<<128, 128, 0, stream>>>(pa, pa, pb);   // A^16
    matmul128<<<128, 128, 0, stream>>>(pb, pb, pa);   // A^32
    matmul128<<<128, 128, 0, stream>>>(pa, pa, pb);   // A^64

    // x -> bf16
    f32_to_bf16_k<<<dim3((M_TOK * 1024 / 8 + 255) / 256), dim3(256), 0, stream>>>(
        x, xb, M_TOK * 1024 / 8);
    // all weight converts, one launch
    wconv6<<<dim3(512, 6), dim3(256), 0, stream>>>(
        s_w1, s_w2, B_w, C_w, D_w, g_w,
        w1b, w2b, Bwb, Cwb, Dwb, gwb,
        512 * 1024 / 8, 128 * 512 / 8, 128 * 1024 / 8, 1024 * 128 / 8,
        1024 * 1024 / 8, 1024 * 1024 / 8);

    // z1 = silu(x @ s_w1^T + s_b1)
    gemm256<0><<<dim3(128), dim3(512), 0, stream>>>(
        xb, w1b, s_b1, nullptr, nullptr, nullptr, nullptr, nullptr, z1b);
    // u = (x @ B_w^T + B_b) * sigmoid(z1 @ s_w2^T + s_b2)
    gemm_u<<<dim3(256), dim3(256), 0, stream>>>(z1b, w2b, s_b2, xb, Bwb, B_b, ub);

    // chunked scan
    ssm_phase1<<<256, 128, 0, stream>>>(A, ub, Ebuf);
    ssm_phase2<<<8, 128, 0, stream>>>(pb, Ebuf, startbuf);
    ssm_phase3<<<256, 128, 0, stream>>>(A, ub, startbuf, hsb);

    // gate = sigmoid(x @ g_w^T + g_b)  (bf16 buffer)
    gemm256<1><<<dim3(256), dim3(512), 0, stream>>>(
        xb, gwb, g_b, nullptr, nullptr, nullptr, nullptr, nullptr, gateb);
    // out = (x @ D_w^T + D_b + hs @ C_w^T + C_b) * gate
    gemm256<2><<<dim3(256), dim3(512), 0, stream>>>(
        xb, Dwb, D_b, C_b, hsb, Cwb, gateb, out, nullptr);
}

// Round 5
// 292.729 us; speedup vs baseline: 1.5232x; 1.0308x over previous
//
#include <hip/hip_runtime.h>
#include <hip/hip_bf16.h>

typedef __bf16 bf16x8 __attribute__((ext_vector_type(8)));
typedef float f32x4 __attribute__((ext_vector_type(4)));

#define M_TOK 16384   // 8 * 2048 tokens
#define CHUNK 64
#define NCHUNK 32     // 2048 / 64

__device__ __forceinline__ void gload16(const void* g, void* l) {
    __builtin_amdgcn_global_load_lds(
        (const __attribute__((address_space(1))) void*)g,
        (__attribute__((address_space(3))) void*)l, 16, 0, 0);
}

__device__ __forceinline__ float sigmoidf_(float v) { return 1.f / (1.f + __expf(-v)); }

#define BARRIER __builtin_amdgcn_s_barrier()
#define LGKM0 do { asm volatile("s_waitcnt lgkmcnt(0)" ::: "memory"); __builtin_amdgcn_sched_barrier(0); } while (0)
#define VMC(n) asm volatile("s_waitcnt vmcnt(" #n ")" ::: "memory")

// ---------------- fp32 -> bf16 bulk convert (vectorized) ----------------
__global__ __launch_bounds__(256) void f32_to_bf16_k(const float* __restrict__ in,
                                                     __hip_bfloat16* __restrict__ out, int n8) {
    int i = blockIdx.x * 256 + threadIdx.x;
    if (i >= n8) return;
    const f32x4* p4 = reinterpret_cast<const f32x4*>(in) + (size_t)i * 2;
    f32x4 a = p4[0], b = p4[1];
    union { __hip_bfloat16 h[8]; uint4 u; } o;
    o.h[0] = __float2bfloat16(a[0]); o.h[1] = __float2bfloat16(a[1]);
    o.h[2] = __float2bfloat16(a[2]); o.h[3] = __float2bfloat16(a[3]);
    o.h[4] = __float2bfloat16(b[0]); o.h[5] = __float2bfloat16(b[1]);
    o.h[6] = __float2bfloat16(b[2]); o.h[7] = __float2bfloat16(b[3]);
    *reinterpret_cast<uint4*>(out + (size_t)i * 8) = o.u;
}

// ---------------- all 6 weight converts in ONE launch (blockIdx.y selects tensor) ----------------
__global__ __launch_bounds__(256)
void wconv6(const float* s0, const float* s1, const float* s2, const float* s3,
            const float* s4, const float* s5,
            __hip_bfloat16* d0, __hip_bfloat16* d1, __hip_bfloat16* d2,
            __hip_bfloat16* d3, __hip_bfloat16* d4, __hip_bfloat16* d5,
            int n0, int n1, int n2, int n3, int n4, int n5) {
    const float* src; __hip_bfloat16* dst; int n8;
    switch (blockIdx.y) {
        case 0: src = s0; dst = d0; n8 = n0; break;
        case 1: src = s1; dst = d1; n8 = n1; break;
        case 2: src = s2; dst = d2; n8 = n2; break;
        case 3: src = s3; dst = d3; n8 = n3; break;
        case 4: src = s4; dst = d4; n8 = n4; break;
        default: src = s5; dst = d5; n8 = n5; break;
    }
    int i = blockIdx.x * 256 + threadIdx.x;
    if (i >= n8) return;
    const f32x4* p4 = reinterpret_cast<const f32x4*>(src) + (size_t)i * 2;
    f32x4 a = p4[0], b = p4[1];
    union { __hip_bfloat16 h[8]; uint4 u; } o;
    o.h[0] = __float2bfloat16(a[0]); o.h[1] = __float2bfloat16(a[1]);
    o.h[2] = __float2bfloat16(a[2]); o.h[3] = __float2bfloat16(a[3]);
    o.h[4] = __float2bfloat16(b[0]); o.h[5] = __float2bfloat16(b[1]);
    o.h[6] = __float2bfloat16(b[2]); o.h[7] = __float2bfloat16(b[3]);
    *reinterpret_cast<uint4*>(dst + (size_t)i * 8) = o.u;
}

// ---------------- stage one half-tile (128 rows x 64 cols bf16), pre-swizzled source ----------------
// LDS dest is LINEAR [128][64] bf16 (row = 128 B). Logical element (r, colbyte c) readable at
// LDS byte r*128 + (c ^ swz(r)), swz(r) = ((r>>2)&3)<<5. gload_lds writes linearly, so we load
// from global col (c ^ swz) into linear col c (XOR involution; rule #21 both-sides).
__device__ __forceinline__ void stage_half(const __hip_bfloat16* src, int ldk, size_t row0,
                                           int k0, char* lds_half, int tid) {
    const int lane = tid & 63, wid = tid >> 6;
    #pragma unroll
    for (int l = 0; l < 2; ++l) {
        int q = wid * 2 + l;                 // 0..15 (1 KB chunk)
        int r = q * 8 + (lane >> 3);         // row within half
        int sw = ((r >> 2) & 3) << 5;        // swizzle (bytes)
        int cb = ((lane & 7) * 16) ^ sw;     // pre-swizzled source col byte
        const char* g = (const char*)(src + (row0 + r) * (size_t)ldk + k0) + cb;
        gload16(g, lds_half + q * 1024 + lane * 16);
    }
}

// ================= 256x256 pipelined GEMM: out = epi(X[M,K] @ W[N,K]^T + bias) =========
// MODE 0: silu -> bf16 (N=512)  | MODE 1: sigmoid -> bf16 (N=1024)
// MODE 2: (X@W^T + b + HS@CW^T + b2) * gate -> f32 (N=1024, K=1024+128)
//
// R4 schedule: ALL 4 half-tiles of kt+1 burst-issued at top of tile kt (8 loads/wave).
// Issue-to-use = one full tile (~latency-covering). Waits (per-wave outstanding):
// steady: p0 vmcnt(12) [kt.h0,h1], p1 vmcnt(10) [kt.h2], p2 vmcnt(8) [kt.h3];
// last tile (no staging): 4 / 2 / 0. Four barriers per tile (was 8).
#define READ_A(ARR, MOFF)                                                      \
    { _Pragma("unroll") for (int m_ = 0; m_ < 4; ++m_)                         \
      _Pragma("unroll") for (int kk_ = 0; kk_ < 2; ++kk_)                      \
          ARR[m_][kk_] = frag(Ab, ((MOFF) + m_) * 32 + wm16 + lr, kk_); }
#define READ_B(NOFF)                                                           \
    { _Pragma("unroll") for (int n_ = 0; n_ < 2; ++n_)                         \
      _Pragma("unroll") for (int kk_ = 0; kk_ < 2; ++kk_)                      \
          bC[n_][kk_] = frag(Bb_, ((NOFF) + n_) * 64 + wn16 + lr, kk_); }
#define MFMA_Q(A, MB, NB)                                                      \
    { _Pragma("unroll") for (int kk_ = 0; kk_ < 2; ++kk_)                      \
      _Pragma("unroll") for (int m_ = 0; m_ < 4; ++m_)                         \
      _Pragma("unroll") for (int n_ = 0; n_ < 2; ++n_)                         \
          acc[(MB) + m_][(NB) + n_] = __builtin_amdgcn_mfma_f32_16x16x32_bf16( \
              A[m_][kk_], bC[n_][kk_], acc[(MB) + m_][(NB) + n_], 0, 0, 0); }
#define TILE_BODY(KT, STG, WA, WB, WC)                                         \
    {                                                                          \
        char* Ab  = smem + (((KT) & 1) ? 65536 : 0);                           \
        char* Bb_ = Ab + 32768;                                                \
        if (STG) { stage(KT + 1, 0); stage(KT + 1, 1);                         \
                   stage(KT + 1, 2); stage(KT + 1, 3); }                       \
        WA; BARRIER;                                                           \
        READ_A(aH, 0); READ_B(0); LGKM0;                                       \
        __builtin_amdgcn_s_setprio(1); MFMA_Q(aH, 0, 0); __builtin_amdgcn_s_setprio(0); \
        WB; BARRIER;                                                           \
        READ_A(aC, 4); LGKM0;                                                  \
        __builtin_amdgcn_s_setprio(1); MFMA_Q(aC, 4, 0); __builtin_amdgcn_s_setprio(0); \
        WC; BARRIER;                                                           \
        READ_B(2); LGKM0;                                                      \
        __builtin_amdgcn_s_setprio(1); MFMA_Q(aC, 4, 2); MFMA_Q(aH, 0, 2);     \
        __builtin_amdgcn_s_setprio(0);                                         \
        BARRIER;                                                               \
    }

template<int MODE>
__global__ __launch_bounds__(512, 2)
void gemm256(const __hip_bfloat16* __restrict__ X, const __hip_bfloat16* __restrict__ W,
             const float* __restrict__ bias, const float* __restrict__ bias2,
             const __hip_bfloat16* __restrict__ HS, const __hip_bfloat16* __restrict__ CW,
             const __hip_bfloat16* __restrict__ gate, float* __restrict__ outF,
             __hip_bfloat16* __restrict__ outB) {
    __shared__ char smem[131072];                 // 2 buffers x (A[256][64] + B[256][64]) bf16
    constexpr int N  = (MODE == 0) ? 512 : 1024;
    constexpr int NT = (MODE == 2) ? 18 : 16;     // MODE2: 16 K-tiles X@W + 2 K-tiles HS@CW
    constexpr int nN = N / 256;

    const int nwg  = gridDim.x;
    const int orig = blockIdx.x;
    const int v    = (orig & 7) * (nwg >> 3) + (orig >> 3);   // XCD-bijective (nwg%8==0)
    const size_t m0 = (size_t)(v / nN) * 256;
    const int    n0 = (v % nN) * 256;
    const int tid = threadIdx.x, lane = tid & 63, wid = tid >> 6;
    const int wm = wid >> 2, wn = wid & 3;
    const int lr = lane & 15, lg = lane >> 4;
    const int wm16 = wm * 16, wn16 = wn * 16;

    auto frag = [&](const char* base, int R, int kk2) -> bf16x8 {
        int cb = (kk2 * 64 + lg * 16) ^ (((R >> 2) & 3) << 5);
        return *reinterpret_cast<const bf16x8*>(base + R * 128 + cb);
    };
    auto stage = [&](int kt, int half) {
        char* buf = smem + ((kt & 1) ? 65536 : 0);
        bool cp = (MODE == 2) && (kt >= 16);
        const __hip_bfloat16* a = cp ? HS : X;
        const __hip_bfloat16* b = cp ? CW : W;
        int ldk = cp ? 128 : 1024;
        int k0  = cp ? (kt - 16) * 64 : kt * 64;
        switch (half) {
            case 0: stage_half(a, ldk, m0,             k0, buf,                 tid); break;
            case 1: stage_half(b, ldk, (size_t)n0,     k0, buf + 32768,         tid); break;
            case 2: stage_half(a, ldk, m0 + 128,       k0, buf + 16384,         tid); break;
            default: stage_half(b, ldk, (size_t)n0 + 128, k0, buf + 32768 + 16384, tid); break;
        }
    };

    f32x4 acc[8][4] = {};
    bf16x8 aH[4][2], aC[4][2], bC[2][2];

    // prologue: burst-stage tile 0 (8 loads); waits happen inside TILE_BODY
    stage(0, 0); stage(0, 1); stage(0, 2); stage(0, 3);

    for (int kt = 0; kt < NT - 1; ++kt)
        TILE_BODY(kt, true, VMC(12), VMC(10), VMC(8))
    TILE_BODY(NT - 1, false, VMC(4), VMC(2), VMC(0))

    // epilogue
    #pragma unroll
    for (int m = 0; m < 8; ++m)
        #pragma unroll
        for (int n = 0; n < 4; ++n)
            #pragma unroll
            for (int rr = 0; rr < 4; ++rr) {
                size_t row = m0 + m * 32 + wm16 + lg * 4 + rr;
                int col = n0 + n * 64 + wn16 + lr;
                float vv = acc[m][n][rr] + bias[col];
                if constexpr (MODE == 0) {
                    outB[row * N + col] = __float2bfloat16(vv * sigmoidf_(vv));
                } else if constexpr (MODE == 1) {
                    outB[row * N + col] = __float2bfloat16(sigmoidf_(vv));
                } else {
                    float y = vv + bias2[col];
                    float gv = __bfloat162float(gate[row * 1024 + col]);
                    outF[row * 1024 + col] = y * gv;
                }
            }
}

// ---------------- u = (x@B_w^T + B_b) * sigmoid(z1@s_w2^T + s_b2)   [16384,128] ----------------
__global__ __launch_bounds__(256)
void gemm_u(const __hip_bfloat16* __restrict__ Z1, const __hip_bfloat16* __restrict__ W2,
            const float* __restrict__ b2,
            const __hip_bfloat16* __restrict__ X, const __hip_bfloat16* __restrict__ Bw,
            const float* __restrict__ Bb, __hip_bfloat16* __restrict__ U) {
    __shared__ __align__(16) __hip_bfloat16 As[64 * 64];
    __shared__ __align__(16) __hip_bfloat16 Bs[128 * 64];
    const int orig = blockIdx.x;                 // nwg = 256
    const int v = (orig & 7) * 32 + (orig >> 3);
    const int m0 = v * 64;
    const int tid = threadIdx.x;
    const int wid = tid >> 6, lane = tid & 63;
    const int wm = wid >> 1, wn = wid & 1;
    const int lr = lane & 15, lg = lane >> 4;
    const int srow = tid >> 3, sc8 = tid & 7;

    f32x4 accS[2][4] = {};
    for (int k0 = 0; k0 < 512; k0 += 64) {
        __syncthreads();
        #pragma unroll
        for (int j = 0; j < 2; ++j) {
            int row = srow + j * 32, q = tid + 256 * j;
            gload16(&Z1[(size_t)(m0 + row) * 512 + k0 + sc8 * 8], &As[q * 8]);
        }
        #pragma unroll
        for (int j = 0; j < 4; ++j) {
            int row = srow + j * 32, q = tid + 256 * j;
            gload16(&W2[(size_t)row * 512 + k0 + sc8 * 8], &Bs[q * 8]);
        }
        __syncthreads();
        #pragma unroll
        for (int kk = 0; kk < 2; ++kk) {
            bf16x8 af[2], bfr[4];
            #pragma unroll
            for (int m = 0; m < 2; ++m)
                af[m] = *reinterpret_cast<const bf16x8*>(&As[(wm*32 + m*16 + lr) * 64 + kk*32 + lg*8]);
            #pragma unroll
            for (int n = 0; n < 4; ++n)
                bfr[n] = *reinterpret_cast<const bf16x8*>(&Bs[(wn*64 + n*16 + lr) * 64 + kk*32 + lg*8]);
            #pragma unroll
            for (int m = 0; m < 2; ++m)
                #pragma unroll
                for (int n = 0; n < 4; ++n)
                    accS[m][n] = __builtin_amdgcn_mfma_f32_16x16x32_bf16(af[m], bfr[n], accS[m][n], 0, 0, 0);
        }
    }
    #pragma unroll
    for (int m = 0; m < 2; ++m)
        #pragma unroll
        for (int n = 0; n < 4; ++n)
            #pragma unroll
            for (int r = 0; r < 4; ++r) {
                int col = wn*64 + n*16 + lr;
                accS[m][n][r] = sigmoidf_(accS[m][n][r] + b2[col]);
            }
    f32x4 accU[2][4] = {};
    for (int k0 = 0; k0 < 1024; k0 += 64) {
        __syncthreads();
        #pragma unroll
        for (int j = 0; j < 2; ++j) {
            int row = srow + j * 32, q = tid + 256 * j;
            gload16(&X[(size_t)(m0 + row) * 1024 + k0 + sc8 * 8], &As[q * 8]);
        }
        #pragma unroll
        for (int j = 0; j < 4; ++j) {
            int row = srow + j * 32, q = tid + 256 * j;
            gload16(&Bw[(size_t)row * 1024 + k0 + sc8 * 8], &Bs[q * 8]);
        }
        __syncthreads();
        #pragma unroll
        for (int kk = 0; kk < 2; ++kk) {
            bf16x8 af[2], bfr[4];
            #pragma unroll
            for (int m = 0; m < 2; ++m)
                af[m] = *reinterpret_cast<const bf16x8*>(&As[(wm*32 + m*16 + lr) * 64 + kk*32 + lg*8]);
            #pragma unroll
            for (int n = 0; n < 4; ++n)
                bfr[n] = *reinterpret_cast<const bf16x8*>(&Bs[(wn*64 + n*16 + lr) * 64 + kk*32 + lg*8]);
            #pragma unroll
            for (int m = 0; m < 2; ++m)
                #pragma unroll
                for (int n = 0; n < 4; ++n)
                    accU[m][n] = __builtin_amdgcn_mfma_f32_16x16x32_bf16(af[m], bfr[n], accU[m][n], 0, 0, 0);
        }
    }
    #pragma unroll
    for (int m = 0; m < 2; ++m)
        #pragma unroll
        for (int n = 0; n < 4; ++n)
            #pragma unroll
            for (int r = 0; r < 4; ++r) {
                int row = m0 + wm*32 + m*16 + lg*4 + r;
                int col = wn*64 + n*16 + lr;
                float uval = (accU[m][n][r] + Bb[col]) * accS[m][n][r];
                U[(size_t)row * 128 + col] = __float2bfloat16(uval);
            }
}

// ---------------- P^8 column-wise: block j computes col j via 7 matvecs (fp32 exact) ---------
// 128 blocks x 128 threads; A LDS-resident. Two chained launches give A^8 then A^64.
// (Replaces 6 dependent matmul128 launches ~24us; NOT single-block — R2's apow64 lesson.)
__global__ __launch_bounds__(128) void matpow8(const float* __restrict__ P,
                                               float* __restrict__ O) {
    __shared__ float Pl[128 * 132];
    __shared__ __align__(16) float v[2][128];
    const int tid = threadIdx.x, j = blockIdx.x;
    #pragma unroll 8
    for (int r = 0; r < 128; ++r) Pl[r * 132 + tid] = P[r * 128 + tid];
    v[0][tid] = P[tid * 128 + j];    // column j
    __syncthreads();
    int cur = 0;
    for (int it = 0; it < 7; ++it) {
        const f32x4* row = reinterpret_cast<const f32x4*>(&Pl[tid * 132]);
        const f32x4* hv  = reinterpret_cast<const f32x4*>(v[cur]);
        f32x4 s4 = {0.f, 0.f, 0.f, 0.f};
        #pragma unroll
        for (int k = 0; k < 32; ++k) s4 += row[k] * hv[k];
        v[cur ^ 1][tid] = s4[0] + s4[1] + s4[2] + s4[3];
        __syncthreads();
        cur ^= 1;
    }
    O[tid * 128 + j] = v[cur][tid];
}

// ---------------- chunked scan phase 1: local chunk-end states (zero init) ----------------
__global__ __launch_bounds__(128) void ssm_phase1(const float* __restrict__ A,
                                                  const __hip_bfloat16* __restrict__ u,
                                                  float* __restrict__ E) {
    __shared__ float Al[128 * 132];
    __shared__ __align__(16) float hbuf[2][128];
    const int tid = threadIdx.x;
    #pragma unroll 8
    for (int r = 0; r < 128; ++r) Al[r * 132 + tid] = A[r * 128 + tid];
    hbuf[0][tid] = 0.f;
    __syncthreads();
    const int b = blockIdx.x >> 5, c = blockIdx.x & 31;
    const __hip_bfloat16* up = u + ((size_t)b * 2048 + c * CHUNK) * 128;
    const f32x4* Arow = reinterpret_cast<const f32x4*>(&Al[tid * 132]);
    int cur = 0;
    for (int t = 0; t < CHUNK; ++t) {
        const f32x4* hv = reinterpret_cast<const f32x4*>(hbuf[cur]);
        f32x4 s4 = {0.f, 0.f, 0.f, 0.f};
        #pragma unroll
        for (int k = 0; k < 32; ++k) s4 += Arow[k] * hv[k];
        float val = s4[0] + s4[1] + s4[2] + s4[3] + __bfloat162float(up[t * 128 + tid]);
        hbuf[cur ^ 1][tid] = val;
        __syncthreads();
        cur ^= 1;
    }
    E[(size_t)blockIdx.x * 128 + tid] = hbuf[cur][tid];
}

// ---------------- phase 2: per-batch sequential combine across chunks with A^64 ----------------
__global__ __launch_bounds__(128) void ssm_phase2(const float* __restrict__ A64,
                                                  const float* __restrict__ E,
                                                  float* __restrict__ starts) {
    __shared__ float Al[128 * 132];
    __shared__ __align__(16) float st[2][128];
    const int tid = threadIdx.x;
    const int b = blockIdx.x;     // 8 blocks, one per batch
    #pragma unroll 8
    for (int r = 0; r < 128; ++r) Al[r * 132 + tid] = A64[r * 128 + tid];
    st[0][tid] = 0.f;
    __syncthreads();
    const f32x4* Arow = reinterpret_cast<const f32x4*>(&Al[tid * 132]);
    int cur = 0;
    for (int c = 0; c < NCHUNK; ++c) {
        starts[((size_t)b * NCHUNK + c) * 128 + tid] = st[cur][tid];
        const f32x4* hv = reinterpret_cast<const f32x4*>(st[cur]);
        f32x4 s4 = {0.f, 0.f, 0.f, 0.f};
        #pragma unroll
        for (int k = 0; k < 32; ++k) s4 += Arow[k] * hv[k];
        float val = s4[0] + s4[1] + s4[2] + s4[3] + E[((size_t)b * NCHUNK + c) * 128 + tid];
        st[cur ^ 1][tid] = val;
        __syncthreads();
        cur ^= 1;
    }
}

// ---------------- phase 3: re-run local scans from correct starts, emit hs (bf16) ----------------
__global__ __launch_bounds__(128) void ssm_phase3(const float* __restrict__ A,
                                                  const __hip_bfloat16* __restrict__ u,
                                                  const float* __restrict__ starts,
                                                  __hip_bfloat16* __restrict__ hs) {
    __shared__ float Al[128 * 132];
    __shared__ __align__(16) float hbuf[2][128];
    const int tid = threadIdx.x;
    #pragma unroll 8
    for (int r = 0; r < 128; ++r) Al[r * 132 + tid] = A[r * 128 + tid];
    hbuf[0][tid] = starts[(size_t)blockIdx.x * 128 + tid];
    __syncthreads();
    const int b = blockIdx.x >> 5, c = blockIdx.x & 31;
    const size_t tok0 = (size_t)b * 2048 + c * CHUNK;
    const __hip_bfloat16* up = u + tok0 * 128;
    const f32x4* Arow = reinterpret_cast<const f32x4*>(&Al[tid * 132]);
    int cur = 0;
    for (int t = 0; t < CHUNK; ++t) {
        const f32x4* hv = reinterpret_cast<const f32x4*>(hbuf[cur]);
        f32x4 s4 = {0.f, 0.f, 0.f, 0.f};
        #pragma unroll
        for (int k = 0; k < 32; ++k) s4 += Arow[k] * hv[k];
        float val = s4[0] + s4[1] + s4[2] + s4[3] + __bfloat162float(up[t * 128 + tid]);
        hs[(tok0 + t) * 128 + tid] = __float2bfloat16(val);
        hbuf[cur ^ 1][tid] = val;
        __syncthreads();
        cur ^= 1;
    }
}

// ---------------- host ----------------
extern "C" void kernel_launch(void* const* d_in, const int* in_sizes, int n_in,
                              void* d_out, int out_size, void* d_ws, size_t ws_size,
                              hipStream_t stream) {
    const float* x    = (const float*)d_in[0];
    const float* A    = (const float*)d_in[1];
    const float* B_w  = (const float*)d_in[2];
    const float* B_b  = (const float*)d_in[3];
    const float* C_w  = (const float*)d_in[4];
    const float* C_b  = (const float*)d_in[5];
    const float* D_w  = (const float*)d_in[6];
    const float* D_b  = (const float*)d_in[7];
    const float* s_w1 = (const float*)d_in[8];
    const float* s_b1 = (const float*)d_in[9];
    const float* s_w2 = (const float*)d_in[10];
    const float* s_b2 = (const float*)d_in[11];
    const float* g_w  = (const float*)d_in[12];
    const float* g_b  = (const float*)d_in[13];
    float* out = (float*)d_out;

    char* p = (char*)d_ws;
    auto alloc = [&](size_t n) { char* r = p; p += (n + 255) & ~(size_t)255; return r; };
    __hip_bfloat16* xb    = (__hip_bfloat16*)alloc((size_t)M_TOK * 1024 * 2);
    __hip_bfloat16* w1b   = (__hip_bfloat16*)alloc(512 * 1024 * 2);
    __hip_bfloat16* w2b   = (__hip_bfloat16*)alloc(128 * 512 * 2);
    __hip_bfloat16* Bwb   = (__hip_bfloat16*)alloc(128 * 1024 * 2);
    __hip_bfloat16* Cwb   = (__hip_bfloat16*)alloc(1024 * 128 * 2);
    __hip_bfloat16* Dwb   = (__hip_bfloat16*)alloc(1024 * 1024 * 2);
    __hip_bfloat16* gwb   = (__hip_bfloat16*)alloc(1024 * 1024 * 2);
    __hip_bfloat16* z1b   = (__hip_bfloat16*)alloc((size_t)M_TOK * 512 * 2);
    __hip_bfloat16* ub    = (__hip_bfloat16*)alloc((size_t)M_TOK * 128 * 2);
    __hip_bfloat16* hsb   = (__hip_bfloat16*)alloc((size_t)M_TOK * 128 * 2);
    __hip_bfloat16* gateb = (__hip_bfloat16*)alloc((size_t)M_TOK * 1024 * 2);
    float* pa       = (float*)alloc(128 * 128 * 4);
    float* pb       = (float*)alloc(128 * 128 * 4);
    float* Ebuf     = (float*)alloc(256 * 128 * 4);
    float* startbuf = (float*)alloc(256 * 128 * 4);

    // A^64 = (A^8)^8 via two column-matvec kernels (fp32 exact)
    matpow8<<<128, 128, 0, stream>>>(A,  pa);   // A^8
    matpow8<<<128, 128, 0, stream>>>(pa, pb);   // A^64

    // x -> bf16
    f32_to_bf16_k<<<dim3((M_TOK * 1024 / 8 + 255) / 256), dim3(256), 0, stream>>>(
        x, xb, M_TOK * 1024 / 8);
    // all weight converts, one launch
    wconv6<<<dim3(512, 6), dim3(256), 0, stream>>>(
        s_w1, s_w2, B_w, C_w, D_w, g_w,
        w1b, w2b, Bwb, Cwb, Dwb, gwb,
        512 * 1024 / 8, 128 * 512 / 8, 128 * 1024 / 8, 1024 * 128 / 8,
        1024 * 1024 / 8, 1024 * 1024 / 8);

    // z1 = silu(x @ s_w1^T + s_b1)
    gemm256<0><<<dim3(128), dim3(512), 0, stream>>>(
        xb, w1b, s_b1, nullptr, nullptr, nullptr, nullptr, nullptr, z1b);
    // u = (x @ B_w^T + B_b) * sigmoid(z1 @ s_w2^T + s_b2)
    gemm_u<<<dim3(256), dim3(256), 0, stream>>>(z1b, w2b, s_b2, xb, Bwb, B_b, ub);

    // chunked scan
    ssm_phase1<<<256, 128, 0, stream>>>(A, ub, Ebuf);
    ssm_phase2<<<8, 128, 0, stream>>>(pb, Ebuf, startbuf);
    ssm_phase3<<<256, 128, 0, stream>>>(A, ub, startbuf, hsb);

    // gate = sigmoid(x @ g_w^T + g_b)  (bf16 buffer)
    gemm256<1><<<dim3(256), dim3(512), 0, stream>>>(
        xb, gwb, g_b, nullptr, nullptr, nullptr, nullptr, nullptr, gateb);
    // out = (x @ D_w^T + D_b + hs @ C_w^T + C_b) * gate
    gemm256<2><<<dim3(256), dim3(512), 0, stream>>>(
        xb, Dwb, D_b, C_b, hsb, Cwb, gateb, out, nullptr);
}

// Round 6
// 264.747 us; speedup vs baseline: 1.6842x; 1.1057x over previous
//
#include <hip/hip_runtime.h>
#include <hip/hip_bf16.h>

typedef __bf16 bf16x8 __attribute__((ext_vector_type(8)));
typedef float f32x4 __attribute__((ext_vector_type(4)));

#define M_TOK 16384   // 8 * 2048 tokens
#define CHUNK 64
#define NCHUNK 32     // 2048 / 64

__device__ __forceinline__ void gload16(const void* g, void* l) {
    __builtin_amdgcn_global_load_lds(
        (const __attribute__((address_space(1))) void*)g,
        (__attribute__((address_space(3))) void*)l, 16, 0, 0);
}

__device__ __forceinline__ float sigmoidf_(float v) { return 1.f / (1.f + __expf(-v)); }

#define BARRIER __builtin_amdgcn_s_barrier()
#define VMC(n) asm volatile("s_waitcnt vmcnt(" #n ")" ::: "memory")

// ---------------- fp32 -> bf16 bulk convert (vectorized) ----------------
__global__ __launch_bounds__(256) void f32_to_bf16_k(const float* __restrict__ in,
                                                     __hip_bfloat16* __restrict__ out, int n8) {
    int i = blockIdx.x * 256 + threadIdx.x;
    if (i >= n8) return;
    const f32x4* p4 = reinterpret_cast<const f32x4*>(in) + (size_t)i * 2;
    f32x4 a = p4[0], b = p4[1];
    union { __hip_bfloat16 h[8]; uint4 u; } o;
    o.h[0] = __float2bfloat16(a[0]); o.h[1] = __float2bfloat16(a[1]);
    o.h[2] = __float2bfloat16(a[2]); o.h[3] = __float2bfloat16(a[3]);
    o.h[4] = __float2bfloat16(b[0]); o.h[5] = __float2bfloat16(b[1]);
    o.h[6] = __float2bfloat16(b[2]); o.h[7] = __float2bfloat16(b[3]);
    *reinterpret_cast<uint4*>(out + (size_t)i * 8) = o.u;
}

// ---------------- all 6 weight converts in ONE launch (blockIdx.y selects tensor) ----------------
__global__ __launch_bounds__(256)
void wconv6(const float* s0, const float* s1, const float* s2, const float* s3,
            const float* s4, const float* s5,
            __hip_bfloat16* d0, __hip_bfloat16* d1, __hip_bfloat16* d2,
            __hip_bfloat16* d3, __hip_bfloat16* d4, __hip_bfloat16* d5,
            int n0, int n1, int n2, int n3, int n4, int n5) {
    const float* src; __hip_bfloat16* dst; int n8;
    switch (blockIdx.y) {
        case 0: src = s0; dst = d0; n8 = n0; break;
        case 1: src = s1; dst = d1; n8 = n1; break;
        case 2: src = s2; dst = d2; n8 = n2; break;
        case 3: src = s3; dst = d3; n8 = n3; break;
        case 4: src = s4; dst = d4; n8 = n4; break;
        default: src = s5; dst = d5; n8 = n5; break;
    }
    int i = blockIdx.x * 256 + threadIdx.x;
    if (i >= n8) return;
    const f32x4* p4 = reinterpret_cast<const f32x4*>(src) + (size_t)i * 2;
    f32x4 a = p4[0], b = p4[1];
    union { __hip_bfloat16 h[8]; uint4 u; } o;
    o.h[0] = __float2bfloat16(a[0]); o.h[1] = __float2bfloat16(a[1]);
    o.h[2] = __float2bfloat16(a[2]); o.h[3] = __float2bfloat16(a[3]);
    o.h[4] = __float2bfloat16(b[0]); o.h[5] = __float2bfloat16(b[1]);
    o.h[6] = __float2bfloat16(b[2]); o.h[7] = __float2bfloat16(b[3]);
    *reinterpret_cast<uint4*>(dst + (size_t)i * 8) = o.u;
}

// ---------------- stage one half-tile (128 rows x 64 cols bf16), pre-swizzled source ----------------
// Swizzle (G4-verified): logical (r, colbyte c) lives at LDS byte r*128 + (c ^ ((r&7)<<4)).
// gload_lds writes linearly, so the SOURCE col is pre-XORed (involution; rule #21 both-sides).
__device__ __forceinline__ void stage_half(const __hip_bfloat16* src, int ldk, size_t row0,
                                           int k0, char* lds_half, int tid) {
    const int lane = tid & 63, wid = tid >> 6;
    #pragma unroll
    for (int l = 0; l < 2; ++l) {
        int q = wid * 2 + l;                 // 0..15 (1 KB chunk)
        int r = q * 8 + (lane >> 3);         // row within half
        int cb = ((lane & 7) * 16) ^ ((r & 7) << 4);   // pre-swizzled source col byte
        const char* g = (const char*)(src + (row0 + r) * (size_t)ldk + k0) + cb;
        gload16(g, lds_half + q * 1024 + lane * 16);
    }
}

// ================= 256x256 GEMM, 2-barrier/tile, counted vmcnt, compiler-scheduled =========
// MODE 0: silu -> bf16 (N=512)  | MODE 1: sigmoid -> bf16 (N=1024)
// MODE 2: (X@W^T + b + HS@CW^T + b2) * gate -> f32 (N=1024, K=1024+128)
//
// Per tile: [vmcnt(2), BARRIER] stage 4 halves of kt+1; compute Q00+Q10 (A0,A1,B0) —
// compiler-free region; [vmcnt(8) drains own B1, BARRIER] compute Q11+Q01 (B1).
// No lgkmcnt pins / sched_barriers (m141: pinning regresses). Waits never 0 except last tile.
#define READ_A(ARR, MOFF)                                                      \
    { _Pragma("unroll") for (int m_ = 0; m_ < 4; ++m_)                         \
      _Pragma("unroll") for (int kk_ = 0; kk_ < 2; ++kk_)                      \
          ARR[m_][kk_] = frag(Ab, ((MOFF) + m_) * 32 + wm16 + lr, kk_); }
#define READ_B(ARR, NOFF)                                                      \
    { _Pragma("unroll") for (int n_ = 0; n_ < 2; ++n_)                         \
      _Pragma("unroll") for (int kk_ = 0; kk_ < 2; ++kk_)                      \
          ARR[n_][kk_] = frag(Bb_, ((NOFF) + n_) * 64 + wn16 + lr, kk_); }
#define MFMA_Q(A, B, MB, NB)                                                   \
    { _Pragma("unroll") for (int kk_ = 0; kk_ < 2; ++kk_)                      \
      _Pragma("unroll") for (int m_ = 0; m_ < 4; ++m_)                         \
      _Pragma("unroll") for (int n_ = 0; n_ < 2; ++n_)                         \
          acc[(MB) + m_][(NB) + n_] = __builtin_amdgcn_mfma_f32_16x16x32_bf16( \
              A[m_][kk_], B[n_][kk_], acc[(MB) + m_][(NB) + n_], 0, 0, 0); }

template<int MODE>
__global__ __launch_bounds__(512, 2)
void gemm256(const __hip_bfloat16* __restrict__ X, const __hip_bfloat16* __restrict__ W,
             const float* __restrict__ bias, const float* __restrict__ bias2,
             const __hip_bfloat16* __restrict__ HS, const __hip_bfloat16* __restrict__ CW,
             const __hip_bfloat16* __restrict__ gate, float* __restrict__ outF,
             __hip_bfloat16* __restrict__ outB) {
    __shared__ char smem[131072];                 // 2 buffers x (A[256][64] + B[256][64]) bf16
    constexpr int N  = (MODE == 0) ? 512 : 1024;
    constexpr int NT = (MODE == 2) ? 18 : 16;     // MODE2: 16 K-tiles X@W + 2 K-tiles HS@CW
    constexpr int nN = N / 256;

    const int nwg  = gridDim.x;
    const int orig = blockIdx.x;
    const int v    = (orig & 7) * (nwg >> 3) + (orig >> 3);   // XCD-bijective (nwg%8==0)
    const size_t m0 = (size_t)(v / nN) * 256;
    const int    n0 = (v % nN) * 256;
    const int tid = threadIdx.x, lane = tid & 63, wid = tid >> 6;
    const int wm = wid >> 2, wn = wid & 3;
    const int lr = lane & 15, lg = lane >> 4;
    const int wm16 = wm * 16, wn16 = wn * 16;

    auto frag = [&](const char* base, int R, int kk2) -> bf16x8 {
        int cb = (kk2 * 64 + lg * 16) ^ ((R & 7) << 4);
        return *reinterpret_cast<const bf16x8*>(base + R * 128 + cb);
    };
    auto stage = [&](int kt, int half) {
        char* buf = smem + ((kt & 1) ? 65536 : 0);
        bool cp = (MODE == 2) && (kt >= 16);
        const __hip_bfloat16* a = cp ? HS : X;
        const __hip_bfloat16* b = cp ? CW : W;
        int ldk = cp ? 128 : 1024;
        int k0  = cp ? (kt - 16) * 64 : kt * 64;
        switch (half) {
            case 0: stage_half(a, ldk, m0,             k0, buf,                 tid); break;
            case 1: stage_half(b, ldk, (size_t)n0,     k0, buf + 32768,         tid); break;
            case 2: stage_half(a, ldk, m0 + 128,       k0, buf + 16384,         tid); break;
            default: stage_half(b, ldk, (size_t)n0 + 128, k0, buf + 32768 + 16384, tid); break;
        }
    };

    f32x4 acc[8][4] = {};
    bf16x8 aH[4][2], aC[4][2], bLo[2][2], bHi[2][2];

    // prologue: stage tile 0 (A0,B0,A1,B1)
    stage(0, 0); stage(0, 1); stage(0, 2); stage(0, 3);

    for (int kt = 0; kt < NT; ++kt) {
        const bool stg = kt < NT - 1;
        // need A0,B0,A1 of kt landed (collectively): own B1 (2 loads) may still fly
        VMC(2);
        BARRIER;
        {
            char* Ab  = smem + ((kt & 1) ? 65536 : 0);
            char* Bb_ = Ab + 32768;
            if (stg) { stage(kt + 1, 0); stage(kt + 1, 1); stage(kt + 1, 2); stage(kt + 1, 3); }
            READ_A(aH, 0); READ_A(aC, 4); READ_B(bLo, 0);
            MFMA_Q(aH, bLo, 0, 0); MFMA_Q(aC, bLo, 4, 0);
        }
        // drain own B1 of kt (oldest) past the 8 just-staged loads of kt+1
        if (stg) { VMC(8); } else { VMC(0); }
        BARRIER;
        {
            char* Ab  = smem + ((kt & 1) ? 65536 : 0);
            char* Bb_ = Ab + 32768;
            READ_B(bHi, 2);
            MFMA_Q(aC, bHi, 4, 2); MFMA_Q(aH, bHi, 0, 2);
        }
    }

    // epilogue
    #pragma unroll
    for (int m = 0; m < 8; ++m)
        #pragma unroll
        for (int n = 0; n < 4; ++n)
            #pragma unroll
            for (int rr = 0; rr < 4; ++rr) {
                size_t row = m0 + m * 32 + wm16 + lg * 4 + rr;
                int col = n0 + n * 64 + wn16 + lr;
                float vv = acc[m][n][rr] + bias[col];
                if constexpr (MODE == 0) {
                    outB[row * N + col] = __float2bfloat16(vv * sigmoidf_(vv));
                } else if constexpr (MODE == 1) {
                    outB[row * N + col] = __float2bfloat16(sigmoidf_(vv));
                } else {
                    float y = vv + bias2[col];
                    float gv = __bfloat162float(gate[row * 1024 + col]);
                    outF[row * 1024 + col] = y * gv;
                }
            }
}

// ---------------- u = (x@B_w^T + B_b) * sigmoid(z1@s_w2^T + s_b2)   [16384,128] ----------------
// 64x128 tile, swizzled LDS (same (row&7)<<4 involution as gemm256).
__global__ __launch_bounds__(256)
void gemm_u(const __hip_bfloat16* __restrict__ Z1, const __hip_bfloat16* __restrict__ W2,
            const float* __restrict__ b2,
            const __hip_bfloat16* __restrict__ X, const __hip_bfloat16* __restrict__ Bw,
            const float* __restrict__ Bb, __hip_bfloat16* __restrict__ U) {
    __shared__ __align__(16) char As[64 * 128];    // 64 rows x 128 B
    __shared__ __align__(16) char Bs[128 * 128];   // 128 rows x 128 B
    const int orig = blockIdx.x;                 // nwg = 256
    const int v = (orig & 7) * 32 + (orig >> 3);
    const int m0 = v * 64;
    const int tid = threadIdx.x;
    const int wid = tid >> 6, lane = tid & 63;
    const int wm = wid >> 1, wn = wid & 1;
    const int lr = lane & 15, lg = lane >> 4;
    const int srow = tid >> 3, sc8 = tid & 7;

    auto fragA = [&](int R, int kk) -> bf16x8 {
        int cb = (kk * 64 + lg * 16) ^ ((R & 7) << 4);
        return *reinterpret_cast<const bf16x8*>(As + R * 128 + cb);
    };
    auto fragB = [&](int R, int kk) -> bf16x8 {
        int cb = (kk * 64 + lg * 16) ^ ((R & 7) << 4);
        return *reinterpret_cast<const bf16x8*>(Bs + R * 128 + cb);
    };

    f32x4 accS[2][4] = {};
    for (int k0 = 0; k0 < 512; k0 += 64) {
        __syncthreads();
        #pragma unroll
        for (int j = 0; j < 2; ++j) {
            int row = srow + j * 32, q = tid + 256 * j;
            int cb = (sc8 * 16) ^ ((row & 7) << 4);
            gload16((const char*)&Z1[(size_t)(m0 + row) * 512 + k0] + cb, As + q * 16);
        }
        #pragma unroll
        for (int j = 0; j < 4; ++j) {
            int row = srow + j * 32, q = tid + 256 * j;
            int cb = (sc8 * 16) ^ ((row & 7) << 4);
            gload16((const char*)&W2[(size_t)row * 512 + k0] + cb, Bs + q * 16);
        }
        __syncthreads();
        #pragma unroll
        for (int kk = 0; kk < 2; ++kk) {
            bf16x8 af[2], bfr[4];
            #pragma unroll
            for (int m = 0; m < 2; ++m) af[m] = fragA(wm*32 + m*16 + lr, kk);
            #pragma unroll
            for (int n = 0; n < 4; ++n) bfr[n] = fragB(wn*64 + n*16 + lr, kk);
            #pragma unroll
            for (int m = 0; m < 2; ++m)
                #pragma unroll
                for (int n = 0; n < 4; ++n)
                    accS[m][n] = __builtin_amdgcn_mfma_f32_16x16x32_bf16(af[m], bfr[n], accS[m][n], 0, 0, 0);
        }
    }
    #pragma unroll
    for (int m = 0; m < 2; ++m)
        #pragma unroll
        for (int n = 0; n < 4; ++n)
            #pragma unroll
            for (int r = 0; r < 4; ++r) {
                int col = wn*64 + n*16 + lr;
                accS[m][n][r] = sigmoidf_(accS[m][n][r] + b2[col]);
            }
    f32x4 accU[2][4] = {};
    for (int k0 = 0; k0 < 1024; k0 += 64) {
        __syncthreads();
        #pragma unroll
        for (int j = 0; j < 2; ++j) {
            int row = srow + j * 32, q = tid + 256 * j;
            int cb = (sc8 * 16) ^ ((row & 7) << 4);
            gload16((const char*)&X[(size_t)(m0 + row) * 1024 + k0] + cb, As + q * 16);
        }
        #pragma unroll
        for (int j = 0; j < 4; ++j) {
            int row = srow + j * 32, q = tid + 256 * j;
            int cb = (sc8 * 16) ^ ((row & 7) << 4);
            gload16((const char*)&Bw[(size_t)row * 1024 + k0] + cb, Bs + q * 16);
        }
        __syncthreads();
        #pragma unroll
        for (int kk = 0; kk < 2; ++kk) {
            bf16x8 af[2], bfr[4];
            #pragma unroll
            for (int m = 0; m < 2; ++m) af[m] = fragA(wm*32 + m*16 + lr, kk);
            #pragma unroll
            for (int n = 0; n < 4; ++n) bfr[n] = fragB(wn*64 + n*16 + lr, kk);
            #pragma unroll
            for (int m = 0; m < 2; ++m)
                #pragma unroll
                for (int n = 0; n < 4; ++n)
                    accU[m][n] = __builtin_amdgcn_mfma_f32_16x16x32_bf16(af[m], bfr[n], accU[m][n], 0, 0, 0);
        }
    }
    #pragma unroll
    for (int m = 0; m < 2; ++m)
        #pragma unroll
        for (int n = 0; n < 4; ++n)
            #pragma unroll
            for (int r = 0; r < 4; ++r) {
                int row = m0 + wm*32 + m*16 + lg*4 + r;
                int col = wn*64 + n*16 + lr;
                float uval = (accU[m][n][r] + Bb[col]) * accS[m][n][r];
                U[(size_t)row * 128 + col] = __float2bfloat16(uval);
            }
}

// ---------------- P^8 column-wise: block j computes col j via 7 matvecs (fp32 exact) ---------
__global__ __launch_bounds__(128) void matpow8(const float* __restrict__ P,
                                               float* __restrict__ O) {
    __shared__ float Pl[128 * 132];
    __shared__ __align__(16) float v[2][128];
    const int tid = threadIdx.x, j = blockIdx.x;
    #pragma unroll 8
    for (int r = 0; r < 128; ++r) Pl[r * 132 + tid] = P[r * 128 + tid];
    v[0][tid] = P[tid * 128 + j];    // column j
    __syncthreads();
    int cur = 0;
    for (int it = 0; it < 7; ++it) {
        const f32x4* row = reinterpret_cast<const f32x4*>(&Pl[tid * 132]);
        const f32x4* hv  = reinterpret_cast<const f32x4*>(v[cur]);
        f32x4 s4 = {0.f, 0.f, 0.f, 0.f};
        #pragma unroll
        for (int k = 0; k < 32; ++k) s4 += row[k] * hv[k];
        v[cur ^ 1][tid] = s4[0] + s4[1] + s4[2] + s4[3];
        __syncthreads();
        cur ^= 1;
    }
    O[tid * 128 + j] = v[cur][tid];
}

// ---------------- chunked scan phase 1: local chunk-end states (zero init) ----------------
__global__ __launch_bounds__(128) void ssm_phase1(const float* __restrict__ A,
                                                  const __hip_bfloat16* __restrict__ u,
                                                  float* __restrict__ E) {
    __shared__ float Al[128 * 132];
    __shared__ __align__(16) float hbuf[2][128];
    const int tid = threadIdx.x;
    #pragma unroll 8
    for (int r = 0; r < 128; ++r) Al[r * 132 + tid] = A[r * 128 + tid];
    hbuf[0][tid] = 0.f;
    __syncthreads();
    const int b = blockIdx.x >> 5, c = blockIdx.x & 31;
    const __hip_bfloat16* up = u + ((size_t)b * 2048 + c * CHUNK) * 128;
    const f32x4* Arow = reinterpret_cast<const f32x4*>(&Al[tid * 132]);
    int cur = 0;
    for (int t = 0; t < CHUNK; ++t) {
        const f32x4* hv = reinterpret_cast<const f32x4*>(hbuf[cur]);
        f32x4 s4 = {0.f, 0.f, 0.f, 0.f};
        #pragma unroll
        for (int k = 0; k < 32; ++k) s4 += Arow[k] * hv[k];
        float val = s4[0] + s4[1] + s4[2] + s4[3] + __bfloat162float(up[t * 128 + tid]);
        hbuf[cur ^ 1][tid] = val;
        __syncthreads();
        cur ^= 1;
    }
    E[(size_t)blockIdx.x * 128 + tid] = hbuf[cur][tid];
}

// ---------------- phase 2: per-batch sequential combine across chunks with A^64 ----------------
__global__ __launch_bounds__(128) void ssm_phase2(const float* __restrict__ A64,
                                                  const float* __restrict__ E,
                                                  float* __restrict__ starts) {
    __shared__ float Al[128 * 132];
    __shared__ __align__(16) float st[2][128];
    const int tid = threadIdx.x;
    const int b = blockIdx.x;     // 8 blocks, one per batch
    #pragma unroll 8
    for (int r = 0; r < 128; ++r) Al[r * 132 + tid] = A64[r * 128 + tid];
    st[0][tid] = 0.f;
    __syncthreads();
    const f32x4* Arow = reinterpret_cast<const f32x4*>(&Al[tid * 132]);
    int cur = 0;
    for (int c = 0; c < NCHUNK; ++c) {
        starts[((size_t)b * NCHUNK + c) * 128 + tid] = st[cur][tid];
        const f32x4* hv = reinterpret_cast<const f32x4*>(st[cur]);
        f32x4 s4 = {0.f, 0.f, 0.f, 0.f};
        #pragma unroll
        for (int k = 0; k < 32; ++k) s4 += Arow[k] * hv[k];
        float val = s4[0] + s4[1] + s4[2] + s4[3] + E[((size_t)b * NCHUNK + c) * 128 + tid];
        st[cur ^ 1][tid] = val;
        __syncthreads();
        cur ^= 1;
    }
}

// ---------------- phase 3: re-run local scans from correct starts, emit hs (bf16) ----------------
__global__ __launch_bounds__(128) void ssm_phase3(const float* __restrict__ A,
                                                  const __hip_bfloat16* __restrict__ u,
                                                  const float* __restrict__ starts,
                                                  __hip_bfloat16* __restrict__ hs) {
    __shared__ float Al[128 * 132];
    __shared__ __align__(16) float hbuf[2][128];
    const int tid = threadIdx.x;
    #pragma unroll 8
    for (int r = 0; r < 128; ++r) Al[r * 132 + tid] = A[r * 128 + tid];
    hbuf[0][tid] = starts[(size_t)blockIdx.x * 128 + tid];
    __syncthreads();
    const int b = blockIdx.x >> 5, c = blockIdx.x & 31;
    const size_t tok0 = (size_t)b * 2048 + c * CHUNK;
    const __hip_bfloat16* up = u + tok0 * 128;
    const f32x4* Arow = reinterpret_cast<const f32x4*>(&Al[tid * 132]);
    int cur = 0;
    for (int t = 0; t < CHUNK; ++t) {
        const f32x4* hv = reinterpret_cast<const f32x4*>(hbuf[cur]);
        f32x4 s4 = {0.f, 0.f, 0.f, 0.f};
        #pragma unroll
        for (int k = 0; k < 32; ++k) s4 += Arow[k] * hv[k];
        float val = s4[0] + s4[1] + s4[2] + s4[3] + __bfloat162float(up[t * 128 + tid]);
        hs[(tok0 + t) * 128 + tid] = __float2bfloat16(val);
        hbuf[cur ^ 1][tid] = val;
        __syncthreads();
        cur ^= 1;
    }
}

// ---------------- host ----------------
extern "C" void kernel_launch(void* const* d_in, const int* in_sizes, int n_in,
                              void* d_out, int out_size, void* d_ws, size_t ws_size,
                              hipStream_t stream) {
    const float* x    = (const float*)d_in[0];
    const float* A    = (const float*)d_in[1];
    const float* B_w  = (const float*)d_in[2];
    const float* B_b  = (const float*)d_in[3];
    const float* C_w  = (const float*)d_in[4];
    const float* C_b  = (const float*)d_in[5];
    const float* D_w  = (const float*)d_in[6];
    const float* D_b  = (const float*)d_in[7];
    const float* s_w1 = (const float*)d_in[8];
    const float* s_b1 = (const float*)d_in[9];
    const float* s_w2 = (const float*)d_in[10];
    const float* s_b2 = (const float*)d_in[11];
    const float* g_w  = (const float*)d_in[12];
    const float* g_b  = (const float*)d_in[13];
    float* out = (float*)d_out;

    char* p = (char*)d_ws;
    auto alloc = [&](size_t n) { char* r = p; p += (n + 255) & ~(size_t)255; return r; };
    __hip_bfloat16* xb    = (__hip_bfloat16*)alloc((size_t)M_TOK * 1024 * 2);
    __hip_bfloat16* w1b   = (__hip_bfloat16*)alloc(512 * 1024 * 2);
    __hip_bfloat16* w2b   = (__hip_bfloat16*)alloc(128 * 512 * 2);
    __hip_bfloat16* Bwb   = (__hip_bfloat16*)alloc(128 * 1024 * 2);
    __hip_bfloat16* Cwb   = (__hip_bfloat16*)alloc(1024 * 128 * 2);
    __hip_bfloat16* Dwb   = (__hip_bfloat16*)alloc(1024 * 1024 * 2);
    __hip_bfloat16* gwb   = (__hip_bfloat16*)alloc(1024 * 1024 * 2);
    __hip_bfloat16* z1b   = (__hip_bfloat16*)alloc((size_t)M_TOK * 512 * 2);
    __hip_bfloat16* ub    = (__hip_bfloat16*)alloc((size_t)M_TOK * 128 * 2);
    __hip_bfloat16* hsb   = (__hip_bfloat16*)alloc((size_t)M_TOK * 128 * 2);
    __hip_bfloat16* gateb = (__hip_bfloat16*)alloc((size_t)M_TOK * 1024 * 2);
    float* pa       = (float*)alloc(128 * 128 * 4);
    float* pb       = (float*)alloc(128 * 128 * 4);
    float* Ebuf     = (float*)alloc(256 * 128 * 4);
    float* startbuf = (float*)alloc(256 * 128 * 4);

    // A^64 = (A^8)^8 via two column-matvec kernels (fp32 exact)
    matpow8<<<128, 128, 0, stream>>>(A,  pa);   // A^8
    matpow8<<<128, 128, 0, stream>>>(pa, pb);   // A^64

    // x -> bf16
    f32_to_bf16_k<<<dim3((M_TOK * 1024 / 8 + 255) / 256), dim3(256), 0, stream>>>(
        x, xb, M_TOK * 1024 / 8);
    // all weight converts, one launch
    wconv6<<<dim3(512, 6), dim3(256), 0, stream>>>(
        s_w1, s_w2, B_w, C_w, D_w, g_w,
        w1b, w2b, Bwb, Cwb, Dwb, gwb,
        512 * 1024 / 8, 128 * 512 / 8, 128 * 1024 / 8, 1024 * 128 / 8,
        1024 * 1024 / 8, 1024 * 1024 / 8);

    // z1 = silu(x @ s_w1^T + s_b1)
    gemm256<0><<<dim3(128), dim3(512), 0, stream>>>(
        xb, w1b, s_b1, nullptr, nullptr, nullptr, nullptr, nullptr, z1b);
    // u = (x @ B_w^T + B_b) * sigmoid(z1 @ s_w2^T + s_b2)
    gemm_u<<<dim3(256), dim3(256), 0, stream>>>(z1b, w2b, s_b2, xb, Bwb, B_b, ub);

    // chunked scan
    ssm_phase1<<<256, 128, 0, stream>>>(A, ub, Ebuf);
    ssm_phase2<<<8, 128, 0, stream>>>(pb, Ebuf, startbuf);
    ssm_phase3<<<256, 128, 0, stream>>>(A, ub, startbuf, hsb);

    // gate = sigmoid(x @ g_w^T + g_b)  (bf16 buffer)
    gemm256<1><<<dim3(256), dim3(512), 0, stream>>>(
        xb, gwb, g_b, nullptr, nullptr, nullptr, nullptr, nullptr, gateb);
    // out = (x @ D_w^T + D_b + hs @ C_w^T + C_b) * gate
    gemm256<2><<<dim3(256), dim3(512), 0, stream>>>(
        xb, Dwb, D_b, C_b, hsb, Cwb, gateb, out, nullptr);
}